// Round 1
// baseline (1791.633 us; speedup 1.0000x reference)
//
#include <hip/hip_runtime.h>
#include <cstdint>
#include <math.h>

#define NN 50000
#define EE 800000
#define GG 64
#define IN_DIM 512
#define HIDC 128
#define OUT_DIM 64
#define NEG_SLOPE 0.2f
#define BN_EPS 1e-5f

// ---------------- utility ----------------
__global__ void k_memset32(int* p, int val, int n) {
    int i = blockIdx.x * blockDim.x + threadIdx.x;
    int stride = gridDim.x * blockDim.x;
    for (; i < n; i += stride) p[i] = val;
}

__device__ inline float leaky(float x) { return x > 0.f ? x : NEG_SLOPE * x; }

__device__ inline void atomicMaxF(float* addr, float val) {
    if (val >= 0.f)
        atomicMax((int*)addr, __float_as_int(val));
    else
        atomicMin((unsigned int*)addr, (unsigned int)__float_as_int(val));
}

__device__ inline float waveReduceSum(float v) {
    for (int off = 32; off > 0; off >>= 1) v += __shfl_down(v, off, 64);
    return v;
}

// ---------------- GEMM: C[NR,M] = A[NR,K] @ B[K,M], f32 ----------------
#define GBM 128
#define GBN 64
#define GBK 16
__global__ __launch_bounds__(256) void k_gemm(const float* __restrict__ A,
                                              const float* __restrict__ B,
                                              float* __restrict__ C,
                                              int NR, int K, int M) {
    __shared__ float As[GBK][GBM + 4];
    __shared__ float Bs[GBK][GBN + 4];
    int tid = threadIdx.x;
    int tx = tid & 15, ty = tid >> 4;
    int rowBase = blockIdx.y * GBM;
    int colBase = blockIdx.x * GBN;
    float acc[8][4] = {};
    for (int k0 = 0; k0 < K; k0 += GBK) {
#pragma unroll
        for (int i = 0; i < 8; i++) {
            int idx = i * 256 + tid;
            int r = idx >> 4, kk = idx & 15;
            int row = rowBase + r;
            As[kk][r] = (row < NR) ? A[row * K + k0 + kk] : 0.f;
        }
#pragma unroll
        for (int i = 0; i < 4; i++) {
            int idx = i * 256 + tid;
            int kk = idx >> 6, c = idx & 63;
            Bs[kk][c] = B[(k0 + kk) * M + colBase + c];
        }
        __syncthreads();
#pragma unroll
        for (int kk = 0; kk < GBK; kk++) {
            float a[8], b[4];
#pragma unroll
            for (int i = 0; i < 8; i++) a[i] = As[kk][ty * 8 + i];
#pragma unroll
            for (int j = 0; j < 4; j++) b[j] = Bs[kk][tx * 4 + j];
#pragma unroll
            for (int i = 0; i < 8; i++)
#pragma unroll
                for (int j = 0; j < 4; j++) acc[i][j] += a[i] * b[j];
        }
        __syncthreads();
    }
#pragma unroll
    for (int i = 0; i < 8; i++) {
        int row = rowBase + ty * 8 + i;
        if (row < NN) {
#pragma unroll
            for (int j = 0; j < 4; j++)
                C[row * M + colBase + tx * 4 + j] = acc[i][j];
        }
    }
}

// ---------------- attention scores ----------------
// blockDim = M (= H*128), one block per node
__global__ void k_scores(const float* __restrict__ xl, const float* __restrict__ asrc,
                         const float* __restrict__ adst, float* __restrict__ es,
                         float* __restrict__ ed, int H, int M) {
    int n = blockIdx.x;
    int t = threadIdx.x;
    float v = xl[n * M + t];
    float ps = v * asrc[t], pd = v * adst[t];
    ps = waveReduceSum(ps);
    pd = waveReduceSum(pd);
    __shared__ float sS[4], sD[4];
    int wid = t >> 6;
    if ((t & 63) == 0) { sS[wid] = ps; sD[wid] = pd; }
    __syncthreads();
    if (t < H) {
        es[n * H + t] = sS[2 * t] + sS[2 * t + 1];
        ed[n * H + t] = sD[2 * t] + sD[2 * t + 1];
    }
}

// m = self-loop score, den = 0
__global__ void k_init_mden(const float* __restrict__ es, const float* __restrict__ ed,
                            float* __restrict__ m, float* __restrict__ den, int nh) {
    int i = blockIdx.x * blockDim.x + threadIdx.x;
    if (i < nh) {
        m[i] = leaky(es[i] + ed[i]);
        den[i] = 0.f;
    }
}

__global__ void k_edge_max(const int* __restrict__ src, const int* __restrict__ dst,
                           const float* __restrict__ es, const float* __restrict__ ed,
                           float* __restrict__ escore, float* __restrict__ m, int H) {
    int e = blockIdx.x * blockDim.x + threadIdx.x;
    if (e >= EE) return;
    int s = src[e], d = dst[e];
    for (int h = 0; h < H; h++) {
        float sc = leaky(es[s * H + h] + ed[d * H + h]);
        escore[e * H + h] = sc;
        atomicMaxF(&m[d * H + h], sc);
    }
}

__global__ void k_edge_exp(const int* __restrict__ dst, const float* __restrict__ escore,
                           const float* __restrict__ m, float* __restrict__ den,
                           const int* __restrict__ pos_of_e, float* __restrict__ exsorted,
                           int H) {
    int e = blockIdx.x * blockDim.x + threadIdx.x;
    if (e >= EE) return;
    int d = dst[e];
    int p = pos_of_e[e];
    for (int h = 0; h < H; h++) {
        float ex = expf(escore[e * H + h] - m[d * H + h]);
        atomicAdd(&den[d * H + h], ex);
        exsorted[p * H + h] = ex;
    }
}

// one block (M threads) per node; sorted incoming edges
__global__ void k_aggregate(const float* __restrict__ xl, const float* __restrict__ es,
                            const float* __restrict__ ed, const float* __restrict__ m,
                            const float* __restrict__ den, const float* __restrict__ exsorted,
                            const int* __restrict__ offsets, const int* __restrict__ count,
                            const int* __restrict__ ssrc, const float* __restrict__ bias,
                            float* __restrict__ out, int H, int M) {
    int n = blockIdx.x;
    int t = threadIdx.x;
    int h = t >> 7;
    float self_sc = leaky(es[n * H + h] + ed[n * H + h]);
    float mx = m[n * H + h];
    float ex_self = expf(self_sc - mx);
    float acc = ex_self * xl[n * M + t];
    int s0 = offsets[n];
    int cnt = count[n];
    for (int i = 0; i < cnt; i++) {
        int srcn = ssrc[s0 + i];
        float exv = exsorted[(s0 + i) * H + h];
        acc += exv * xl[srcn * M + t];
    }
    float d = den[n * H + h] + ex_self + 1e-16f;
    out[n * M + t] = acc / d + bias[t];
}

// ---------------- edge sort by dst (counting sort) ----------------
__global__ void k_count(const int* __restrict__ dst, int* __restrict__ count) {
    int e = blockIdx.x * blockDim.x + threadIdx.x;
    if (e < EE) atomicAdd(&count[dst[e]], 1);
}

__global__ void k_scan_local(const int* __restrict__ in, int* __restrict__ out_excl,
                             int* __restrict__ bsums, int n) {
    __shared__ int s[256];
    int tid = threadIdx.x;
    int i = blockIdx.x * 256 + tid;
    int v = (i < n) ? in[i] : 0;
    s[tid] = v;
    __syncthreads();
    for (int off = 1; off < 256; off <<= 1) {
        int t_ = (tid >= off) ? s[tid - off] : 0;
        __syncthreads();
        s[tid] += t_;
        __syncthreads();
    }
    if (i < n) out_excl[i] = s[tid] - v;
    if (tid == 255) bsums[blockIdx.x] = s[255];
}

__global__ void k_scan_sums(int* __restrict__ b, int n) {
    __shared__ int s[256];
    int tid = threadIdx.x;
    int v = (tid < n) ? b[tid] : 0;
    s[tid] = v;
    __syncthreads();
    for (int off = 1; off < 256; off <<= 1) {
        int t_ = (tid >= off) ? s[tid - off] : 0;
        __syncthreads();
        s[tid] += t_;
        __syncthreads();
    }
    if (tid < n) b[tid] = s[tid] - v;
}

__global__ void k_scan_add(int* __restrict__ out_excl, const int* __restrict__ bsums, int n) {
    int i = blockIdx.x * 256 + threadIdx.x;
    if (i < n) out_excl[i] += bsums[blockIdx.x];
}

__global__ void k_scatter(const int* __restrict__ src, const int* __restrict__ dst,
                          const int* __restrict__ offsets, int* __restrict__ cursor,
                          int* __restrict__ ssrc, int* __restrict__ pos_of_e) {
    int e = blockIdx.x * blockDim.x + threadIdx.x;
    if (e >= EE) return;
    int d = dst[e];
    int p = offsets[d] + atomicAdd(&cursor[d], 1);
    ssrc[p] = src[e];
    pos_of_e[e] = p;
}

// ---------------- batch norm ----------------
__global__ void k_bn_stats(const float* __restrict__ h, double* __restrict__ stats) {
    int t = threadIdx.x;  // 256 cols
    int r0 = blockIdx.x * 256;
    int rend = min(r0 + 256, NN);
    double s = 0.0, s2 = 0.0;
    for (int r = r0; r < rend; r++) {
        float v = h[r * 256 + t];
        s += v;
        s2 += (double)v * v;
    }
    atomicAdd(&stats[t], s);
    atomicAdd(&stats[256 + t], s2);
}

__global__ void k_bn_finalize(const double* __restrict__ stats, const float* __restrict__ g,
                              const float* __restrict__ be, float* __restrict__ scale,
                              float* __restrict__ shift) {
    int t = threadIdx.x;  // 256
    double mu = stats[t] / (double)NN;
    double var = stats[256 + t] / (double)NN - mu * mu;
    float sc = (float)((double)g[t] / sqrt(var + (double)BN_EPS));
    scale[t] = sc;
    shift[t] = be[t] - (float)mu * sc;
}

__global__ void k_bn_apply(float* __restrict__ h, const float* __restrict__ scale,
                           const float* __restrict__ shift) {
    int i = blockIdx.x * blockDim.x + threadIdx.x;
    int stride = gridDim.x * blockDim.x;
    int total = NN * 256;
    for (; i < total; i += stride) {
        int t = i & 255;
        float v = h[i] * scale[t] + shift[t];
        h[i] = v > 0.f ? v : 0.f;
    }
}

// ---------------- pooling + final linear ----------------
#define POOL_ROWS 128
__global__ void k_pool(const float* __restrict__ h3, const int* __restrict__ batch,
                       float* __restrict__ pooled, int* __restrict__ cnt) {
    int t = threadIdx.x;  // 128
    int r0 = blockIdx.x * POOL_ROWS;
    if (r0 >= NN) return;
    int rend = min(r0 + POOL_ROWS, NN);
    float acc = 0.f;
    int c_acc = 0;
    int g_cur = batch[r0];
    for (int r = r0; r < rend; r++) {
        int g = batch[r];
        if (g != g_cur) {
            atomicAdd(&pooled[g_cur * 128 + t], acc);
            if (t == 0) atomicAdd(&cnt[g_cur], c_acc);
            acc = 0.f;
            c_acc = 0;
            g_cur = g;
        }
        acc += h3[r * 128 + t];
        c_acc++;
    }
    atomicAdd(&pooled[g_cur * 128 + t], acc);
    if (t == 0) atomicAdd(&cnt[g_cur], c_acc);
}

__global__ void k_final(const float* __restrict__ pooled, const int* __restrict__ cnt,
                        const float* __restrict__ Wlin, const float* __restrict__ blin,
                        float* __restrict__ out) {
    int g = blockIdx.x;   // 64
    int o = threadIdx.x;  // 64
    float c = (float)max(cnt[g], 1);
    float acc = 0.f;
    for (int k = 0; k < 128; k++) acc += pooled[g * 128 + k] * Wlin[k * 64 + o];
    out[g * 64 + o] = acc / c + blin[o];
}

// ---------------- host ----------------
extern "C" void kernel_launch(void* const* d_in, const int* in_sizes, int n_in,
                              void* d_out, int out_size, void* d_ws, size_t ws_size,
                              hipStream_t stream) {
    const float* x = (const float*)d_in[0];
    const int* ei = (const int*)d_in[1];
    const int* batch = (const int*)d_in[2];
    const float* W1 = (const float*)d_in[3];
    const float* as1 = (const float*)d_in[4];
    const float* ad1 = (const float*)d_in[5];
    const float* b1 = (const float*)d_in[6];
    const float* g1 = (const float*)d_in[7];
    const float* be1 = (const float*)d_in[8];
    const float* W2 = (const float*)d_in[9];
    const float* as2 = (const float*)d_in[10];
    const float* ad2 = (const float*)d_in[11];
    const float* b2 = (const float*)d_in[12];
    const float* g2 = (const float*)d_in[13];
    const float* be2 = (const float*)d_in[14];
    const float* W3 = (const float*)d_in[15];
    const float* as3 = (const float*)d_in[16];
    const float* ad3 = (const float*)d_in[17];
    const float* b3 = (const float*)d_in[18];
    const float* Wlin = (const float*)d_in[19];
    const float* blin = (const float*)d_in[20];
    float* out = (float*)d_out;

    const int* src = ei;
    const int* dst = ei + EE;

    char* ws = (char*)d_ws;
    size_t off = 0;
    auto alloc = [&](size_t bytes) -> void* {
        void* p = (void*)(ws + off);
        off = (off + bytes + 255) & ~(size_t)255;
        return p;
    };
    float* xl = (float*)alloc((size_t)NN * 256 * 4);
    float* hbuf = (float*)alloc((size_t)NN * 256 * 4);
    float* es = (float*)alloc((size_t)NN * 2 * 4);
    float* ed = (float*)alloc((size_t)NN * 2 * 4);
    float* m = (float*)alloc((size_t)NN * 2 * 4);
    float* den = (float*)alloc((size_t)NN * 2 * 4);
    float* escore = (float*)alloc((size_t)EE * 2 * 4);
    float* exsorted = (float*)alloc((size_t)EE * 2 * 4);
    int* count = (int*)alloc((size_t)NN * 4);
    int* offsets = (int*)alloc((size_t)NN * 4);
    int* cursor = (int*)alloc((size_t)NN * 4);
    int* ssrc = (int*)alloc((size_t)EE * 4);
    int* pos_of_e = (int*)alloc((size_t)EE * 4);
    int* bsums = (int*)alloc(256 * 4);
    double* bnstats = (double*)alloc(512 * 8);
    float* bnscale = (float*)alloc(256 * 4);
    float* bnshift = (float*)alloc(256 * 4);
    float* pooled = (float*)alloc(64 * 128 * 4);
    int* cnt = (int*)alloc(64 * 4);

    const int EB = (EE + 255) / 256;       // 3125
    const int NB = (NN + 255) / 256;       // 196

    // ---- sort edges by dst (once; graph shared across layers) ----
    k_memset32<<<64, 256, 0, stream>>>(count, 0, NN);
    k_count<<<EB, 256, 0, stream>>>(dst, count);
    k_scan_local<<<NB, 256, 0, stream>>>(count, offsets, bsums, NN);
    k_scan_sums<<<1, 256, 0, stream>>>(bsums, NB);
    k_scan_add<<<NB, 256, 0, stream>>>(offsets, bsums, NN);
    k_memset32<<<64, 256, 0, stream>>>(cursor, 0, NN);
    k_scatter<<<EB, 256, 0, stream>>>(src, dst, offsets, cursor, ssrc, pos_of_e);

    auto run_layer = [&](const float* hin, int K, const float* W, const float* as_,
                         const float* ad_, const float* bias, float* outbuf, int H) {
        int M = H * 128;
        dim3 gg(M / GBN, (NN + GBM - 1) / GBM);
        k_gemm<<<gg, 256, 0, stream>>>(hin, W, xl, NN, K, M);
        k_scores<<<NN, M, 0, stream>>>(xl, as_, ad_, es, ed, H, M);
        int nh = NN * H;
        k_init_mden<<<(nh + 255) / 256, 256, 0, stream>>>(es, ed, m, den, nh);
        k_edge_max<<<EB, 256, 0, stream>>>(src, dst, es, ed, escore, m, H);
        k_edge_exp<<<EB, 256, 0, stream>>>(dst, escore, m, den, pos_of_e, exsorted, H);
        k_aggregate<<<NN, M, 0, stream>>>(xl, es, ed, m, den, exsorted, offsets, count,
                                          ssrc, bias, outbuf, H, M);
    };

    auto bn_relu = [&](float* h, const float* g_, const float* be_) {
        k_memset32<<<4, 256, 0, stream>>>((int*)bnstats, 0, 1024);
        k_bn_stats<<<NB, 256, 0, stream>>>(h, bnstats);
        k_bn_finalize<<<1, 256, 0, stream>>>(bnstats, g_, be_, bnscale, bnshift);
        k_bn_apply<<<2048, 256, 0, stream>>>(h, bnscale, bnshift);
    };

    // layer 1: 512 -> [2,128] concat 256
    run_layer(x, IN_DIM, W1, as1, ad1, b1, hbuf, 2);
    bn_relu(hbuf, g1, be1);
    // layer 2: 256 -> 256
    run_layer(hbuf, 256, W2, as2, ad2, b2, hbuf, 2);
    bn_relu(hbuf, g2, be2);
    // layer 3: 256 -> 128 (1 head, mean == identity)
    run_layer(hbuf, 256, W3, as3, ad3, b3, hbuf, 1);

    // ---- global mean pool + final linear ----
    k_memset32<<<32, 256, 0, stream>>>((int*)pooled, 0, 64 * 128);
    k_memset32<<<1, 64, 0, stream>>>(cnt, 0, 64);
    k_pool<<<(NN + POOL_ROWS - 1) / POOL_ROWS, 128, 0, stream>>>(hbuf, batch, pooled, cnt);
    k_final<<<GG, 64, 0, stream>>>(pooled, cnt, Wlin, blin, out);
}

// Round 2
// 1203.168 us; speedup vs baseline: 1.4891x; 1.4891x over previous
//
#include <hip/hip_runtime.h>
#include <cstdint>
#include <math.h>

#define NN 50000
#define EE 800000
#define GG 64
#define IN_DIM 512
#define NEG_SLOPE 0.2f
#define BN_EPS 1e-5f

typedef short bf16x8 __attribute__((ext_vector_type(8)));
typedef float f32x4 __attribute__((ext_vector_type(4)));

// ---------------- utility ----------------
__global__ void k_memset32(int* p, int val, int n) {
    int i = blockIdx.x * blockDim.x + threadIdx.x;
    int stride = gridDim.x * blockDim.x;
    for (; i < n; i += stride) p[i] = val;
}

__device__ inline float leaky(float x) { return x > 0.f ? x : NEG_SLOPE * x; }

__device__ inline unsigned short f2bf(float f) {
    union { float f; uint32_t u; } v;
    v.f = f;
    uint32_t u = v.u;
    return (unsigned short)((u + 0x7fffu + ((u >> 16) & 1u)) >> 16);
}

__device__ inline void atomicMaxF(float* addr, float val) {
    if (val >= 0.f)
        atomicMax((int*)addr, __float_as_int(val));
    else
        atomicMin((unsigned int*)addr, (unsigned int)__float_as_int(val));
}

__device__ inline float waveReduceSum(float v) {
    for (int off = 32; off > 0; off >>= 1) v += __shfl_down(v, off, 64);
    return v;
}

// ---------------- W transpose + bf16 convert: Wt[m][k] = bf16(W[k][m]) ----------------
__global__ void k_transpose_bf16(const float* __restrict__ W, unsigned short* __restrict__ Wt,
                                 int K, int M) {
    int idx = blockIdx.x * 256 + threadIdx.x;
    if (idx >= K * M) return;
    int k = idx / M, m_ = idx - k * M;
    Wt[(size_t)m_ * K + k] = f2bf(W[idx]);
}

// ---------------- MFMA GEMM: C[NR,M] = A[NR,K](f32) @ Wt[M,K](bf16)^T ----------------
// 128x128 tile, BK=32, 4 waves each computing 64x64 (4x4 frags of 16x16x32)
#define LSTR 40  // LDS row stride in shorts (80B: 16B-aligned, bank-spread)
__global__ __launch_bounds__(256) void k_gemm_mfma(const float* __restrict__ A,
                                                   const unsigned short* __restrict__ Bt,
                                                   float* __restrict__ C,
                                                   int NR, int K, int M) {
    __shared__ unsigned short As[128 * LSTR];
    __shared__ unsigned short Bs[128 * LSTR];
    int tid = threadIdx.x;
    int wave = tid >> 6, lane = tid & 63;
    int r16 = lane & 15, kg = lane >> 4;
    int wr = wave >> 1, wc = wave & 1;
    int rowBase = blockIdx.y * 128;
    int colBase = blockIdx.x * 128;
    f32x4 acc[4][4] = {};
    for (int k0 = 0; k0 < K; k0 += 32) {
#pragma unroll
        for (int c = 0; c < 2; c++) {
            int ch = tid + c * 256;            // 512 chunks of 8 elems
            int row = ch >> 2, kc = (ch & 3) * 8;
            int rg = rowBase + row;
            bf16x8 v = {};
            if (rg < NR) {
                const float4* p = (const float4*)(A + (size_t)rg * K + k0 + kc);
                float4 f0 = p[0], f1 = p[1];
                v[0] = (short)f2bf(f0.x); v[1] = (short)f2bf(f0.y);
                v[2] = (short)f2bf(f0.z); v[3] = (short)f2bf(f0.w);
                v[4] = (short)f2bf(f1.x); v[5] = (short)f2bf(f1.y);
                v[6] = (short)f2bf(f1.z); v[7] = (short)f2bf(f1.w);
            }
            *(bf16x8*)&As[row * LSTR + kc] = v;
            bf16x8 bv = *(const bf16x8*)(Bt + (size_t)(colBase + row) * K + k0 + kc);
            *(bf16x8*)&Bs[row * LSTR + kc] = bv;
        }
        __syncthreads();
        bf16x8 af[4], bfr[4];
#pragma unroll
        for (int m = 0; m < 4; m++)
            af[m] = *(const bf16x8*)&As[(wr * 64 + m * 16 + r16) * LSTR + kg * 8];
#pragma unroll
        for (int n = 0; n < 4; n++)
            bfr[n] = *(const bf16x8*)&Bs[(wc * 64 + n * 16 + r16) * LSTR + kg * 8];
#pragma unroll
        for (int m = 0; m < 4; m++)
#pragma unroll
            for (int n = 0; n < 4; n++)
                acc[m][n] = __builtin_amdgcn_mfma_f32_16x16x32_bf16(af[m], bfr[n], acc[m][n], 0, 0, 0);
        __syncthreads();
    }
    int crow0 = rowBase + wr * 64;
    int ccol = colBase + wc * 64 + r16;
#pragma unroll
    for (int m = 0; m < 4; m++) {
#pragma unroll
        for (int j = 0; j < 4; j++) {
            int row = crow0 + m * 16 + kg * 4 + j;
            if (row < NR) {
#pragma unroll
                for (int n = 0; n < 4; n++)
                    C[(size_t)row * M + ccol + n * 16] = acc[m][n][j];
            }
        }
    }
}

// ---------------- attention scores (+ fused m/den init) ----------------
// blockDim = M (= H*128), one block per node
__global__ void k_scores(const float* __restrict__ xl, const float* __restrict__ asrc,
                         const float* __restrict__ adst, float* __restrict__ es,
                         float* __restrict__ ed, float* __restrict__ m,
                         float* __restrict__ den, int H, int M) {
    int n = blockIdx.x;
    int t = threadIdx.x;
    float v = xl[(size_t)n * M + t];
    float ps = v * asrc[t], pd = v * adst[t];
    ps = waveReduceSum(ps);
    pd = waveReduceSum(pd);
    __shared__ float sS[4], sD[4];
    int wid = t >> 6;
    if ((t & 63) == 0) { sS[wid] = ps; sD[wid] = pd; }
    __syncthreads();
    if (t < H) {
        float e_s = sS[2 * t] + sS[2 * t + 1];
        float e_d = sD[2 * t] + sD[2 * t + 1];
        es[n * H + t] = e_s;
        ed[n * H + t] = e_d;
        m[n * H + t] = leaky(e_s + e_d);  // self-loop score seeds the max
        den[n * H + t] = 0.f;
    }
}

template <int H>
__global__ void k_edge_max(const int* __restrict__ src, const int* __restrict__ dst,
                           const float* __restrict__ es, const float* __restrict__ ed,
                           float* __restrict__ m) {
    int e = blockIdx.x * blockDim.x + threadIdx.x;
    if (e >= EE) return;
    int s = src[e], d = dst[e];
#pragma unroll
    for (int h = 0; h < H; h++) {
        float sc = leaky(es[s * H + h] + ed[d * H + h]);
        atomicMaxF(&m[d * H + h], sc);
    }
}

template <int H>
__global__ void k_edge_exp(const int* __restrict__ src, const int* __restrict__ dst,
                           const float* __restrict__ es, const float* __restrict__ ed,
                           const float* __restrict__ m, float* __restrict__ den,
                           const int* __restrict__ pos_of_e, float* __restrict__ exsorted) {
    int e = blockIdx.x * blockDim.x + threadIdx.x;
    if (e >= EE) return;
    int s = src[e], d = dst[e];
    int p = pos_of_e[e];
#pragma unroll
    for (int h = 0; h < H; h++) {
        float sc = leaky(es[s * H + h] + ed[d * H + h]);
        float ex = __expf(sc - m[d * H + h]);
        atomicAdd(&den[d * H + h], ex);
        exsorted[p * H + h] = ex;
    }
}

// ---------------- aggregation: 1 wave per node, 4 nodes per block ----------------
template <int VEC, int H>  // M = 64*VEC
__global__ __launch_bounds__(256) void k_aggregate(
        const float* __restrict__ xl, const float* __restrict__ es,
        const float* __restrict__ ed, const float* __restrict__ m,
        const float* __restrict__ den, const float* __restrict__ exsorted,
        const int* __restrict__ offsets, const int* __restrict__ count,
        const int* __restrict__ ssrc, const float* __restrict__ bias,
        float* __restrict__ out) {
    const int M = 64 * VEC;
    int n = blockIdx.x * 4 + (threadIdx.x >> 6);
    if (n >= NN) return;
    int lane = threadIdx.x & 63;
    int c0 = lane * VEC;
    int h = c0 >> 7;
    float mx = m[n * H + h];
    float self_sc = leaky(es[n * H + h] + ed[n * H + h]);
    float ex_self = __expf(self_sc - mx);
    float acc[VEC];
    {
        const float* rp = xl + (size_t)n * M + c0;
#pragma unroll
        for (int v = 0; v < VEC; v++) acc[v] = ex_self * rp[v];
    }
    int s0 = offsets[n], cnt = count[n];
    int i = 0;
    for (; i + 2 <= cnt; i += 2) {
        int sA = ssrc[s0 + i], sB = ssrc[s0 + i + 1];
        float eA = exsorted[(s0 + i) * H + h];
        float eB = exsorted[(s0 + i + 1) * H + h];
        const float* rA = xl + (size_t)sA * M + c0;
        const float* rB = xl + (size_t)sB * M + c0;
        float a_[VEC], b_[VEC];
#pragma unroll
        for (int v = 0; v < VEC; v++) a_[v] = rA[v];
#pragma unroll
        for (int v = 0; v < VEC; v++) b_[v] = rB[v];
#pragma unroll
        for (int v = 0; v < VEC; v++) acc[v] += eA * a_[v] + eB * b_[v];
    }
    if (i < cnt) {
        int sA = ssrc[s0 + i];
        float eA = exsorted[(s0 + i) * H + h];
        const float* rA = xl + (size_t)sA * M + c0;
#pragma unroll
        for (int v = 0; v < VEC; v++) acc[v] += eA * rA[v];
    }
    float dsum = den[n * H + h] + ex_self + 1e-16f;
    float inv = 1.f / dsum;
#pragma unroll
    for (int v = 0; v < VEC; v++)
        out[(size_t)n * M + c0 + v] = acc[v] * inv + bias[c0 + v];
}

// ---------------- edge sort by dst (counting sort) ----------------
__global__ void k_count(const int* __restrict__ dst, int* __restrict__ count) {
    int e = blockIdx.x * blockDim.x + threadIdx.x;
    if (e < EE) atomicAdd(&count[dst[e]], 1);
}

__global__ void k_scan_local(const int* __restrict__ in, int* __restrict__ out_excl,
                             int* __restrict__ bsums, int n) {
    __shared__ int s[256];
    int tid = threadIdx.x;
    int i = blockIdx.x * 256 + tid;
    int v = (i < n) ? in[i] : 0;
    s[tid] = v;
    __syncthreads();
    for (int off = 1; off < 256; off <<= 1) {
        int t_ = (tid >= off) ? s[tid - off] : 0;
        __syncthreads();
        s[tid] += t_;
        __syncthreads();
    }
    if (i < n) out_excl[i] = s[tid] - v;
    if (tid == 255) bsums[blockIdx.x] = s[255];
}

__global__ void k_scan_sums(int* __restrict__ b, int n) {
    __shared__ int s[256];
    int tid = threadIdx.x;
    int v = (tid < n) ? b[tid] : 0;
    s[tid] = v;
    __syncthreads();
    for (int off = 1; off < 256; off <<= 1) {
        int t_ = (tid >= off) ? s[tid - off] : 0;
        __syncthreads();
        s[tid] += t_;
        __syncthreads();
    }
    if (tid < n) b[tid] = s[tid] - v;
}

__global__ void k_scan_add(int* __restrict__ out_excl, const int* __restrict__ bsums, int n) {
    int i = blockIdx.x * 256 + threadIdx.x;
    if (i < n) out_excl[i] += bsums[blockIdx.x];
}

__global__ void k_scatter(const int* __restrict__ src, const int* __restrict__ dst,
                          const int* __restrict__ offsets, int* __restrict__ cursor,
                          int* __restrict__ ssrc, int* __restrict__ pos_of_e) {
    int e = blockIdx.x * blockDim.x + threadIdx.x;
    if (e >= EE) return;
    int d = dst[e];
    int p = offsets[d] + atomicAdd(&cursor[d], 1);
    ssrc[p] = src[e];
    pos_of_e[e] = p;
}

// ---------------- batch norm ----------------
__global__ void k_bn_stats(const float* __restrict__ h, double* __restrict__ stats) {
    int t = threadIdx.x;  // 256 cols
    int r0 = blockIdx.x * 256;
    int rend = min(r0 + 256, NN);
    double s = 0.0, s2 = 0.0;
    for (int r = r0; r < rend; r++) {
        float v = h[(size_t)r * 256 + t];
        s += v;
        s2 += (double)v * v;
    }
    atomicAdd(&stats[t], s);
    atomicAdd(&stats[256 + t], s2);
}

__global__ void k_bn_finalize(const double* __restrict__ stats, const float* __restrict__ g,
                              const float* __restrict__ be, float* __restrict__ scale,
                              float* __restrict__ shift) {
    int t = threadIdx.x;  // 256
    double mu = stats[t] / (double)NN;
    double var = stats[256 + t] / (double)NN - mu * mu;
    float sc = (float)((double)g[t] / sqrt(var + (double)BN_EPS));
    scale[t] = sc;
    shift[t] = be[t] - (float)mu * sc;
}

__global__ void k_bn_apply(float* __restrict__ h, const float* __restrict__ scale,
                           const float* __restrict__ shift) {
    int i = blockIdx.x * blockDim.x + threadIdx.x;
    int stride = gridDim.x * blockDim.x;
    int total = NN * 256 / 4;
    float4* h4 = (float4*)h;
    for (; i < total; i += stride) {
        float4 v = h4[i];
        int t = (i * 4) & 255;
        v.x = fmaxf(v.x * scale[t] + shift[t], 0.f);
        v.y = fmaxf(v.y * scale[t + 1] + shift[t + 1], 0.f);
        v.z = fmaxf(v.z * scale[t + 2] + shift[t + 2], 0.f);
        v.w = fmaxf(v.w * scale[t + 3] + shift[t + 3], 0.f);
        h4[i] = v;
    }
}

// ---------------- pooling + final linear ----------------
#define POOL_ROWS 128
__global__ void k_pool(const float* __restrict__ h3, const int* __restrict__ batch,
                       float* __restrict__ pooled, int* __restrict__ cnt) {
    int t = threadIdx.x;  // 128
    int r0 = blockIdx.x * POOL_ROWS;
    if (r0 >= NN) return;
    int rend = min(r0 + POOL_ROWS, NN);
    float acc = 0.f;
    int c_acc = 0;
    int g_cur = batch[r0];
    for (int r = r0; r < rend; r++) {
        int g = batch[r];
        if (g != g_cur) {
            atomicAdd(&pooled[g_cur * 128 + t], acc);
            if (t == 0) atomicAdd(&cnt[g_cur], c_acc);
            acc = 0.f;
            c_acc = 0;
            g_cur = g;
        }
        acc += h3[(size_t)r * 128 + t];
        c_acc++;
    }
    atomicAdd(&pooled[g_cur * 128 + t], acc);
    if (t == 0) atomicAdd(&cnt[g_cur], c_acc);
}

__global__ void k_final(const float* __restrict__ pooled, const int* __restrict__ cnt,
                        const float* __restrict__ Wlin, const float* __restrict__ blin,
                        float* __restrict__ out) {
    int g = blockIdx.x;   // 64
    int o = threadIdx.x;  // 64
    float c = (float)max(cnt[g], 1);
    float acc = 0.f;
    for (int k = 0; k < 128; k++) acc += pooled[g * 128 + k] * Wlin[k * 64 + o];
    out[g * 64 + o] = acc / c + blin[o];
}

// ---------------- host ----------------
extern "C" void kernel_launch(void* const* d_in, const int* in_sizes, int n_in,
                              void* d_out, int out_size, void* d_ws, size_t ws_size,
                              hipStream_t stream) {
    const float* x = (const float*)d_in[0];
    const int* ei = (const int*)d_in[1];
    const int* batch = (const int*)d_in[2];
    const float* W1 = (const float*)d_in[3];
    const float* as1 = (const float*)d_in[4];
    const float* ad1 = (const float*)d_in[5];
    const float* b1 = (const float*)d_in[6];
    const float* g1 = (const float*)d_in[7];
    const float* be1 = (const float*)d_in[8];
    const float* W2 = (const float*)d_in[9];
    const float* as2 = (const float*)d_in[10];
    const float* ad2 = (const float*)d_in[11];
    const float* b2 = (const float*)d_in[12];
    const float* g2 = (const float*)d_in[13];
    const float* be2 = (const float*)d_in[14];
    const float* W3 = (const float*)d_in[15];
    const float* as3 = (const float*)d_in[16];
    const float* ad3 = (const float*)d_in[17];
    const float* b3 = (const float*)d_in[18];
    const float* Wlin = (const float*)d_in[19];
    const float* blin = (const float*)d_in[20];
    float* out = (float*)d_out;

    const int* src = ei;
    const int* dst = ei + EE;

    char* ws = (char*)d_ws;
    size_t off = 0;
    auto alloc = [&](size_t bytes) -> void* {
        void* p = (void*)(ws + off);
        off = (off + bytes + 255) & ~(size_t)255;
        return p;
    };
    float* xl = (float*)alloc((size_t)NN * 256 * 4);
    float* hbuf = (float*)alloc((size_t)NN * 256 * 4);
    unsigned short* Wt = (unsigned short*)alloc((size_t)256 * 512 * 2);
    float* es = (float*)alloc((size_t)NN * 2 * 4);
    float* ed = (float*)alloc((size_t)NN * 2 * 4);
    float* m = (float*)alloc((size_t)NN * 2 * 4);
    float* den = (float*)alloc((size_t)NN * 2 * 4);
    float* exsorted = (float*)alloc((size_t)EE * 2 * 4);
    int* count = (int*)alloc((size_t)NN * 4);
    int* offsets = (int*)alloc((size_t)NN * 4);
    int* cursor = (int*)alloc((size_t)NN * 4);
    int* ssrc = (int*)alloc((size_t)EE * 4);
    int* pos_of_e = (int*)alloc((size_t)EE * 4);
    int* bsums = (int*)alloc(256 * 4);
    double* bnstats = (double*)alloc(512 * 8);
    float* bnscale = (float*)alloc(256 * 4);
    float* bnshift = (float*)alloc(256 * 4);
    float* pooled = (float*)alloc(64 * 128 * 4);
    int* cnt = (int*)alloc(64 * 4);

    const int EB = (EE + 255) / 256;  // 3125
    const int NB = (NN + 255) / 256;  // 196

    // ---- sort edges by dst (once; graph shared across layers) ----
    k_memset32<<<64, 256, 0, stream>>>(count, 0, NN);
    k_count<<<EB, 256, 0, stream>>>(dst, count);
    k_scan_local<<<NB, 256, 0, stream>>>(count, offsets, bsums, NN);
    k_scan_sums<<<1, 256, 0, stream>>>(bsums, NB);
    k_scan_add<<<NB, 256, 0, stream>>>(offsets, bsums, NN);
    k_memset32<<<64, 256, 0, stream>>>(cursor, 0, NN);
    k_scatter<<<EB, 256, 0, stream>>>(src, dst, offsets, cursor, ssrc, pos_of_e);

    auto run_layer = [&](const float* hin, int K, const float* W, const float* as_,
                         const float* ad_, const float* bias, float* outbuf, int H) {
        int M = H * 128;
        k_transpose_bf16<<<(K * M + 255) / 256, 256, 0, stream>>>(W, Wt, K, M);
        dim3 gg(M / 128, (NN + 127) / 128);
        k_gemm_mfma<<<gg, 256, 0, stream>>>(hin, Wt, xl, NN, K, M);
        k_scores<<<NN, M, 0, stream>>>(xl, as_, ad_, es, ed, m, den, H, M);
        if (H == 2) {
            k_edge_max<2><<<EB, 256, 0, stream>>>(src, dst, es, ed, m);
            k_edge_exp<2><<<EB, 256, 0, stream>>>(src, dst, es, ed, m, den, pos_of_e, exsorted);
            k_aggregate<4, 2><<<(NN + 3) / 4, 256, 0, stream>>>(xl, es, ed, m, den, exsorted,
                                                                offsets, count, ssrc, bias, outbuf);
        } else {
            k_edge_max<1><<<EB, 256, 0, stream>>>(src, dst, es, ed, m);
            k_edge_exp<1><<<EB, 256, 0, stream>>>(src, dst, es, ed, m, den, pos_of_e, exsorted);
            k_aggregate<2, 1><<<(NN + 3) / 4, 256, 0, stream>>>(xl, es, ed, m, den, exsorted,
                                                                offsets, count, ssrc, bias, outbuf);
        }
    };

    auto bn_relu = [&](float* h, const float* g_, const float* be_) {
        k_memset32<<<4, 256, 0, stream>>>((int*)bnstats, 0, 1024);
        k_bn_stats<<<NB, 256, 0, stream>>>(h, bnstats);
        k_bn_finalize<<<1, 256, 0, stream>>>(bnstats, g_, be_, bnscale, bnshift);
        k_bn_apply<<<2048, 256, 0, stream>>>(h, bnscale, bnshift);
    };

    // layer 1: 512 -> [2,128] concat 256
    run_layer(x, IN_DIM, W1, as1, ad1, b1, hbuf, 2);
    bn_relu(hbuf, g1, be1);
    // layer 2: 256 -> 256
    run_layer(hbuf, 256, W2, as2, ad2, b2, hbuf, 2);
    bn_relu(hbuf, g2, be2);
    // layer 3: 256 -> 128 (1 head, mean == identity)
    run_layer(hbuf, 256, W3, as3, ad3, b3, hbuf, 1);

    // ---- global mean pool + final linear ----
    k_memset32<<<32, 256, 0, stream>>>((int*)pooled, 0, 64 * 128);
    k_memset32<<<1, 64, 0, stream>>>(cnt, 0, 64);
    k_pool<<<(NN + POOL_ROWS - 1) / POOL_ROWS, 128, 0, stream>>>(hbuf, batch, pooled, cnt);
    k_final<<<GG, 64, 0, stream>>>(pooled, cnt, Wlin, blin, out);
}

// Round 3
// 783.867 us; speedup vs baseline: 2.2856x; 1.5349x over previous
//
#include <hip/hip_runtime.h>
#include <cstdint>
#include <math.h>

#define NN 50000
#define EE 800000
#define GG 64
#define IN_DIM 512
#define NEG_SLOPE 0.2f
#define BN_EPS 1e-5f

typedef short bf16x8 __attribute__((ext_vector_type(8)));
typedef float f32x4 __attribute__((ext_vector_type(4)));

// ---------------- utility ----------------
__global__ void k_memset32(int* p, int val, int n) {
    int i = blockIdx.x * blockDim.x + threadIdx.x;
    int stride = gridDim.x * blockDim.x;
    for (; i < n; i += stride) p[i] = val;
}

__device__ inline float leaky(float x) { return x > 0.f ? x : NEG_SLOPE * x; }

__device__ inline unsigned short f2bf(float f) {
    union { float f; uint32_t u; } v;
    v.f = f;
    uint32_t u = v.u;
    return (unsigned short)((u + 0x7fffu + ((u >> 16) & 1u)) >> 16);
}

__device__ inline float bf2f(unsigned short u) {
    union { uint32_t u; float f; } v;
    v.u = (uint32_t)u << 16;
    return v.f;
}
__device__ inline float bflo(uint32_t u) { return __uint_as_float(u << 16); }
__device__ inline float bfhi(uint32_t u) { return __uint_as_float(u & 0xffff0000u); }
__device__ inline uint32_t packbf(float a, float b) {
    return (uint32_t)f2bf(a) | ((uint32_t)f2bf(b) << 16);
}

__device__ inline float waveReduceSum(float v) {
    for (int off = 32; off > 0; off >>= 1) v += __shfl_down(v, off, 64);
    return v;
}

// ---------------- f32 -> bf16 convert (x input, once) ----------------
__global__ void k_convert_bf16(const float* __restrict__ in, unsigned short* __restrict__ out,
                               int n4) {
    int i = blockIdx.x * blockDim.x + threadIdx.x;
    int stride = gridDim.x * blockDim.x;
    for (; i < n4; i += stride) {
        float4 v = ((const float4*)in)[i];
        uint2 o;
        o.x = packbf(v.x, v.y);
        o.y = packbf(v.z, v.w);
        ((uint2*)out)[i] = o;
    }
}

// ---------------- W transpose + bf16 convert: Wt[m][k] = bf16(W[k][m]) ----------------
__global__ void k_transpose_bf16(const float* __restrict__ W, unsigned short* __restrict__ Wt,
                                 int K, int M) {
    int idx = blockIdx.x * 256 + threadIdx.x;
    if (idx >= K * M) return;
    int k = idx / M, m_ = idx - k * M;
    Wt[(size_t)m_ * K + k] = f2bf(W[idx]);
}

// ---------------- MFMA GEMM: C[NR,M](bf16) = A[NR,K](bf16) @ Wt[M,K](bf16)^T ----------------
// 128x128 tile, BK=32, 4 waves each computing 64x64 (4x4 frags of 16x16x32)
#define LSTR 40  // LDS row stride in shorts (80B: 16B-aligned, bank-spread)
__global__ __launch_bounds__(256) void k_gemm_mfma(const unsigned short* __restrict__ A,
                                                   const unsigned short* __restrict__ Bt,
                                                   unsigned short* __restrict__ C,
                                                   int NR, int K, int M) {
    __shared__ unsigned short As[128 * LSTR];
    __shared__ unsigned short Bs[128 * LSTR];
    int tid = threadIdx.x;
    int wave = tid >> 6, lane = tid & 63;
    int r16 = lane & 15, kg = lane >> 4;
    int wr = wave >> 1, wc = wave & 1;
    int rowBase = blockIdx.y * 128;
    int colBase = blockIdx.x * 128;
    f32x4 acc[4][4] = {};
    for (int k0 = 0; k0 < K; k0 += 32) {
#pragma unroll
        for (int c = 0; c < 2; c++) {
            int ch = tid + c * 256;            // 512 chunks of 8 elems
            int row = ch >> 2, kc = (ch & 3) * 8;
            int rg = rowBase + row;
            bf16x8 v = {};
            if (rg < NR) v = *(const bf16x8*)(A + (size_t)rg * K + k0 + kc);
            *(bf16x8*)&As[row * LSTR + kc] = v;
            bf16x8 bv = *(const bf16x8*)(Bt + (size_t)(colBase + row) * K + k0 + kc);
            *(bf16x8*)&Bs[row * LSTR + kc] = bv;
        }
        __syncthreads();
        bf16x8 af[4], bfr[4];
#pragma unroll
        for (int m = 0; m < 4; m++)
            af[m] = *(const bf16x8*)&As[(wr * 64 + m * 16 + r16) * LSTR + kg * 8];
#pragma unroll
        for (int n = 0; n < 4; n++)
            bfr[n] = *(const bf16x8*)&Bs[(wc * 64 + n * 16 + r16) * LSTR + kg * 8];
#pragma unroll
        for (int m = 0; m < 4; m++)
#pragma unroll
            for (int n = 0; n < 4; n++)
                acc[m][n] = __builtin_amdgcn_mfma_f32_16x16x32_bf16(af[m], bfr[n], acc[m][n], 0, 0, 0);
        __syncthreads();
    }
    int crow0 = rowBase + wr * 64;
    int ccol = colBase + wc * 64 + r16;
#pragma unroll
    for (int m = 0; m < 4; m++) {
#pragma unroll
        for (int j = 0; j < 4; j++) {
            int row = crow0 + m * 16 + kg * 4 + j;
            if (row < NR) {
#pragma unroll
                for (int n = 0; n < 4; n++)
                    C[(size_t)row * M + ccol + n * 16] = f2bf(acc[m][n][j]);
            }
        }
    }
}

// ---------------- attention scores ----------------
// blockDim = M (= H*128), one block per node
__global__ void k_scores(const unsigned short* __restrict__ xl, const float* __restrict__ asrc,
                         const float* __restrict__ adst, float* __restrict__ es,
                         float* __restrict__ ed, int H, int M) {
    int n = blockIdx.x;
    int t = threadIdx.x;
    float v = bf2f(xl[(size_t)n * M + t]);
    float ps = v * asrc[t], pd = v * adst[t];
    ps = waveReduceSum(ps);
    pd = waveReduceSum(pd);
    __shared__ float sS[4], sD[4];
    int wid = t >> 6;
    if ((t & 63) == 0) { sS[wid] = ps; sD[wid] = pd; }
    __syncthreads();
    if (t < H) {
        es[n * H + t] = sS[2 * t] + sS[2 * t + 1];
        ed[n * H + t] = sD[2 * t] + sD[2 * t + 1];
    }
}

// ---------------- fused softmax + aggregation: 1 wave per node ----------------
// VEC bf16 columns per lane; M = 64*VEC. Per-head softmax scalars computed
// redundantly in every lane of the head (broadcast loads, no cross-lane).
template <int VEC, int H>
__global__ __launch_bounds__(256) void k_aggregate(
        const unsigned short* __restrict__ xl, const float* __restrict__ es,
        const float* __restrict__ ed, const int* __restrict__ offsets,
        const int* __restrict__ count, const int* __restrict__ ssrc,
        const float* __restrict__ bias, unsigned short* __restrict__ out) {
    const int M = 64 * VEC;
    int n = blockIdx.x * 4 + (threadIdx.x >> 6);
    if (n >= NN) return;
    int lane = threadIdx.x & 63;
    int c0 = lane * VEC;
    int h = c0 >> 7;
    float edn = ed[n * H + h];
    float self_sc = leaky(es[n * H + h] + edn);
    int s0 = offsets[n], cnt = count[n];
    // pass 1: max
    float mx = self_sc;
    for (int i = 0; i < cnt; i++) {
        int s = ssrc[s0 + i];
        mx = fmaxf(mx, leaky(es[s * H + h] + edn));
    }
    // pass 2: exp + weighted gather
    float ex_self = __expf(self_sc - mx);
    float den = ex_self;
    float acc[VEC];
    {
        const uint32_t* rp = (const uint32_t*)(xl + (size_t)n * M + c0);
#pragma unroll
        for (int v = 0; v < VEC / 2; v++) {
            uint32_t w = rp[v];
            acc[2 * v] = ex_self * bflo(w);
            acc[2 * v + 1] = ex_self * bfhi(w);
        }
    }
    int i = 0;
    for (; i + 2 <= cnt; i += 2) {
        int sA = ssrc[s0 + i], sB = ssrc[s0 + i + 1];
        float eA = __expf(leaky(es[sA * H + h] + edn) - mx);
        float eB = __expf(leaky(es[sB * H + h] + edn) - mx);
        den += eA + eB;
        const uint32_t* rA = (const uint32_t*)(xl + (size_t)sA * M + c0);
        const uint32_t* rB = (const uint32_t*)(xl + (size_t)sB * M + c0);
        uint32_t wa[VEC / 2], wb[VEC / 2];
#pragma unroll
        for (int v = 0; v < VEC / 2; v++) wa[v] = rA[v];
#pragma unroll
        for (int v = 0; v < VEC / 2; v++) wb[v] = rB[v];
#pragma unroll
        for (int v = 0; v < VEC / 2; v++) {
            acc[2 * v] += eA * bflo(wa[v]) + eB * bflo(wb[v]);
            acc[2 * v + 1] += eA * bfhi(wa[v]) + eB * bfhi(wb[v]);
        }
    }
    if (i < cnt) {
        int sA = ssrc[s0 + i];
        float eA = __expf(leaky(es[sA * H + h] + edn) - mx);
        den += eA;
        const uint32_t* rA = (const uint32_t*)(xl + (size_t)sA * M + c0);
#pragma unroll
        for (int v = 0; v < VEC / 2; v++) {
            uint32_t w = rA[v];
            acc[2 * v] += eA * bflo(w);
            acc[2 * v + 1] += eA * bfhi(w);
        }
    }
    float inv = 1.f / (den + 1e-16f);
    uint32_t* op = (uint32_t*)(out + (size_t)n * M + c0);
#pragma unroll
    for (int v = 0; v < VEC / 2; v++) {
        float f0 = acc[2 * v] * inv + bias[c0 + 2 * v];
        float f1 = acc[2 * v + 1] * inv + bias[c0 + 2 * v + 1];
        op[v] = packbf(f0, f1);
    }
}

// ---------------- edge sort by dst (counting sort) ----------------
__global__ void k_count(const int* __restrict__ dst, int* __restrict__ count) {
    int e = blockIdx.x * blockDim.x + threadIdx.x;
    if (e < EE) atomicAdd(&count[dst[e]], 1);
}

__global__ void k_scan_local(const int* __restrict__ in, int* __restrict__ out_excl,
                             int* __restrict__ bsums, int n) {
    __shared__ int s[256];
    int tid = threadIdx.x;
    int i = blockIdx.x * 256 + tid;
    int v = (i < n) ? in[i] : 0;
    s[tid] = v;
    __syncthreads();
    for (int off = 1; off < 256; off <<= 1) {
        int t_ = (tid >= off) ? s[tid - off] : 0;
        __syncthreads();
        s[tid] += t_;
        __syncthreads();
    }
    if (i < n) out_excl[i] = s[tid] - v;
    if (tid == 255) bsums[blockIdx.x] = s[255];
}

__global__ void k_scan_sums(int* __restrict__ b, int n) {
    __shared__ int s[256];
    int tid = threadIdx.x;
    int v = (tid < n) ? b[tid] : 0;
    s[tid] = v;
    __syncthreads();
    for (int off = 1; off < 256; off <<= 1) {
        int t_ = (tid >= off) ? s[tid - off] : 0;
        __syncthreads();
        s[tid] += t_;
        __syncthreads();
    }
    if (tid < n) b[tid] = s[tid] - v;
}

__global__ void k_scan_add(int* __restrict__ out_excl, const int* __restrict__ bsums, int n) {
    int i = blockIdx.x * 256 + threadIdx.x;
    if (i < n) out_excl[i] += bsums[blockIdx.x];
}

__global__ void k_scatter(const int* __restrict__ src, const int* __restrict__ dst,
                          const int* __restrict__ offsets, int* __restrict__ cursor,
                          int* __restrict__ ssrc) {
    int e = blockIdx.x * blockDim.x + threadIdx.x;
    if (e >= EE) return;
    int d = dst[e];
    int p = offsets[d] + atomicAdd(&cursor[d], 1);
    ssrc[p] = src[e];
}

// ---------------- batch norm (bf16 data, f32/f64 stats) ----------------
__global__ void k_bn_stats(const unsigned short* __restrict__ h, double* __restrict__ stats) {
    int t = threadIdx.x;  // 256 cols
    int r0 = blockIdx.x * 256;
    int rend = min(r0 + 256, NN);
    double s = 0.0, s2 = 0.0;
    for (int r = r0; r < rend; r++) {
        float v = bf2f(h[(size_t)r * 256 + t]);
        s += v;
        s2 += (double)v * v;
    }
    atomicAdd(&stats[t], s);
    atomicAdd(&stats[256 + t], s2);
}

__global__ void k_bn_finalize(const double* __restrict__ stats, const float* __restrict__ g,
                              const float* __restrict__ be, float* __restrict__ scale,
                              float* __restrict__ shift) {
    int t = threadIdx.x;  // 256
    double mu = stats[t] / (double)NN;
    double var = stats[256 + t] / (double)NN - mu * mu;
    float sc = (float)((double)g[t] / sqrt(var + (double)BN_EPS));
    scale[t] = sc;
    shift[t] = be[t] - (float)mu * sc;
}

__global__ void k_bn_apply(unsigned short* __restrict__ h, const float* __restrict__ scale,
                           const float* __restrict__ shift) {
    int i = blockIdx.x * blockDim.x + threadIdx.x;
    int stride = gridDim.x * blockDim.x;
    int total = NN * 256 / 8;
    uint4* h4 = (uint4*)h;
    for (; i < total; i += stride) {
        uint4 v = h4[i];
        int t = (i * 8) & 255;
        float f0 = fmaxf(bflo(v.x) * scale[t + 0] + shift[t + 0], 0.f);
        float f1 = fmaxf(bfhi(v.x) * scale[t + 1] + shift[t + 1], 0.f);
        float f2 = fmaxf(bflo(v.y) * scale[t + 2] + shift[t + 2], 0.f);
        float f3 = fmaxf(bfhi(v.y) * scale[t + 3] + shift[t + 3], 0.f);
        float f4 = fmaxf(bflo(v.z) * scale[t + 4] + shift[t + 4], 0.f);
        float f5 = fmaxf(bfhi(v.z) * scale[t + 5] + shift[t + 5], 0.f);
        float f6 = fmaxf(bflo(v.w) * scale[t + 6] + shift[t + 6], 0.f);
        float f7 = fmaxf(bfhi(v.w) * scale[t + 7] + shift[t + 7], 0.f);
        v.x = packbf(f0, f1);
        v.y = packbf(f2, f3);
        v.z = packbf(f4, f5);
        v.w = packbf(f6, f7);
        h4[i] = v;
    }
}

// ---------------- pooling + final linear ----------------
#define POOL_ROWS 128
__global__ void k_pool(const unsigned short* __restrict__ h3, const int* __restrict__ batch,
                       float* __restrict__ pooled, int* __restrict__ cnt) {
    int t = threadIdx.x;  // 128
    int r0 = blockIdx.x * POOL_ROWS;
    if (r0 >= NN) return;
    int rend = min(r0 + POOL_ROWS, NN);
    float acc = 0.f;
    int c_acc = 0;
    int g_cur = batch[r0];
    for (int r = r0; r < rend; r++) {
        int g = batch[r];
        if (g != g_cur) {
            atomicAdd(&pooled[g_cur * 128 + t], acc);
            if (t == 0) atomicAdd(&cnt[g_cur], c_acc);
            acc = 0.f;
            c_acc = 0;
            g_cur = g;
        }
        acc += bf2f(h3[(size_t)r * 128 + t]);
        c_acc++;
    }
    atomicAdd(&pooled[g_cur * 128 + t], acc);
    if (t == 0) atomicAdd(&cnt[g_cur], c_acc);
}

__global__ void k_final(const float* __restrict__ pooled, const int* __restrict__ cnt,
                        const float* __restrict__ Wlin, const float* __restrict__ blin,
                        float* __restrict__ out) {
    int g = blockIdx.x;   // 64
    int o = threadIdx.x;  // 64
    float c = (float)max(cnt[g], 1);
    float acc = 0.f;
    for (int k = 0; k < 128; k++) acc += pooled[g * 128 + k] * Wlin[k * 64 + o];
    out[g * 64 + o] = acc / c + blin[o];
}

// ---------------- host ----------------
extern "C" void kernel_launch(void* const* d_in, const int* in_sizes, int n_in,
                              void* d_out, int out_size, void* d_ws, size_t ws_size,
                              hipStream_t stream) {
    const float* x = (const float*)d_in[0];
    const int* ei = (const int*)d_in[1];
    const int* batch = (const int*)d_in[2];
    const float* W1 = (const float*)d_in[3];
    const float* as1 = (const float*)d_in[4];
    const float* ad1 = (const float*)d_in[5];
    const float* b1 = (const float*)d_in[6];
    const float* g1 = (const float*)d_in[7];
    const float* be1 = (const float*)d_in[8];
    const float* W2 = (const float*)d_in[9];
    const float* as2 = (const float*)d_in[10];
    const float* ad2 = (const float*)d_in[11];
    const float* b2 = (const float*)d_in[12];
    const float* g2 = (const float*)d_in[13];
    const float* be2 = (const float*)d_in[14];
    const float* W3 = (const float*)d_in[15];
    const float* as3 = (const float*)d_in[16];
    const float* ad3 = (const float*)d_in[17];
    const float* b3 = (const float*)d_in[18];
    const float* Wlin = (const float*)d_in[19];
    const float* blin = (const float*)d_in[20];
    float* out = (float*)d_out;

    const int* src = ei;
    const int* dst = ei + EE;

    char* ws = (char*)d_ws;
    size_t off = 0;
    auto alloc = [&](size_t bytes) -> void* {
        void* p = (void*)(ws + off);
        off = (off + bytes + 255) & ~(size_t)255;
        return p;
    };
    unsigned short* xb = (unsigned short*)alloc((size_t)NN * 512 * 2);
    unsigned short* xl = (unsigned short*)alloc((size_t)NN * 256 * 2);
    unsigned short* hbuf = (unsigned short*)alloc((size_t)NN * 256 * 2);
    unsigned short* Wt = (unsigned short*)alloc((size_t)256 * 512 * 2);
    float* es = (float*)alloc((size_t)NN * 2 * 4);
    float* ed = (float*)alloc((size_t)NN * 2 * 4);
    int* count = (int*)alloc((size_t)NN * 4);
    int* offsets = (int*)alloc((size_t)NN * 4);
    int* cursor = (int*)alloc((size_t)NN * 4);
    int* ssrc = (int*)alloc((size_t)EE * 4);
    int* bsums = (int*)alloc(256 * 4);
    double* bnstats = (double*)alloc(512 * 8);
    float* bnscale = (float*)alloc(256 * 4);
    float* bnshift = (float*)alloc(256 * 4);
    float* pooled = (float*)alloc(64 * 128 * 4);
    int* cnt = (int*)alloc(64 * 4);

    const int EB = (EE + 255) / 256;  // 3125
    const int NB = (NN + 255) / 256;  // 196

    // ---- convert x to bf16 (once) ----
    k_convert_bf16<<<2048, 256, 0, stream>>>(x, xb, NN * 512 / 4);

    // ---- sort edges by dst (once; graph shared across layers) ----
    k_memset32<<<64, 256, 0, stream>>>(count, 0, NN);
    k_count<<<EB, 256, 0, stream>>>(dst, count);
    k_scan_local<<<NB, 256, 0, stream>>>(count, offsets, bsums, NN);
    k_scan_sums<<<1, 256, 0, stream>>>(bsums, NB);
    k_scan_add<<<NB, 256, 0, stream>>>(offsets, bsums, NN);
    k_memset32<<<64, 256, 0, stream>>>(cursor, 0, NN);
    k_scatter<<<EB, 256, 0, stream>>>(src, dst, offsets, cursor, ssrc);

    auto run_layer = [&](const unsigned short* hin, int K, const float* W, const float* as_,
                         const float* ad_, const float* bias, unsigned short* outbuf, int H) {
        int M = H * 128;
        k_transpose_bf16<<<(K * M + 255) / 256, 256, 0, stream>>>(W, Wt, K, M);
        dim3 gg(M / 128, (NN + 127) / 128);
        k_gemm_mfma<<<gg, 256, 0, stream>>>(hin, Wt, xl, NN, K, M);
        k_scores<<<NN, M, 0, stream>>>(xl, as_, ad_, es, ed, H, M);
        if (H == 2) {
            k_aggregate<4, 2><<<(NN + 3) / 4, 256, 0, stream>>>(xl, es, ed, offsets, count,
                                                                ssrc, bias, outbuf);
        } else {
            k_aggregate<2, 1><<<(NN + 3) / 4, 256, 0, stream>>>(xl, es, ed, offsets, count,
                                                                ssrc, bias, outbuf);
        }
    };

    auto bn_relu = [&](unsigned short* h, const float* g_, const float* be_) {
        k_memset32<<<4, 256, 0, stream>>>((int*)bnstats, 0, 1024);
        k_bn_stats<<<NB, 256, 0, stream>>>(h, bnstats);
        k_bn_finalize<<<1, 256, 0, stream>>>(bnstats, g_, be_, bnscale, bnshift);
        k_bn_apply<<<2048, 256, 0, stream>>>(h, bnscale, bnshift);
    };

    // layer 1: 512 -> [2,128] concat 256
    run_layer(xb, IN_DIM, W1, as1, ad1, b1, hbuf, 2);
    bn_relu(hbuf, g1, be1);
    // layer 2: 256 -> 256
    run_layer(hbuf, 256, W2, as2, ad2, b2, hbuf, 2);
    bn_relu(hbuf, g2, be2);
    // layer 3: 256 -> 128 (1 head, mean == identity)
    run_layer(hbuf, 256, W3, as3, ad3, b3, hbuf, 1);

    // ---- global mean pool + final linear ----
    k_memset32<<<32, 256, 0, stream>>>((int*)pooled, 0, 64 * 128);
    k_memset32<<<1, 64, 0, stream>>>(cnt, 0, 64);
    k_pool<<<(NN + POOL_ROWS - 1) / POOL_ROWS, 128, 0, stream>>>(hbuf, batch, pooled, cnt);
    k_final<<<GG, 64, 0, stream>>>(pooled, cnt, Wlin, blin, out);
}

// Round 4
// 641.221 us; speedup vs baseline: 2.7941x; 1.2225x over previous
//
#include <hip/hip_runtime.h>
#include <cstdint>
#include <math.h>

#define NN 50000
#define EE 800000
#define GG 64
#define IN_DIM 512
#define NEG_SLOPE 0.2f
#define BN_EPS 1e-5f

typedef short bf16x8 __attribute__((ext_vector_type(8)));
typedef float f32x4 __attribute__((ext_vector_type(4)));

// ---------------- utility ----------------
__global__ void k_memset32(int* p, int val, int n) {
    int i = blockIdx.x * blockDim.x + threadIdx.x;
    int stride = gridDim.x * blockDim.x;
    for (; i < n; i += stride) p[i] = val;
}

__device__ inline float leaky(float x) { return x > 0.f ? x : NEG_SLOPE * x; }

__device__ inline unsigned short f2bf(float f) {
    union { float f; uint32_t u; } v;
    v.f = f;
    uint32_t u = v.u;
    return (unsigned short)((u + 0x7fffu + ((u >> 16) & 1u)) >> 16);
}

__device__ inline float bf2f(unsigned short u) {
    union { uint32_t u; float f; } v;
    v.u = (uint32_t)u << 16;
    return v.f;
}
__device__ inline float bflo(uint32_t u) { return __uint_as_float(u << 16); }
__device__ inline float bfhi(uint32_t u) { return __uint_as_float(u & 0xffff0000u); }
__device__ inline uint32_t packbf(float a, float b) {
    return (uint32_t)f2bf(a) | ((uint32_t)f2bf(b) << 16);
}

__device__ inline float waveReduceSum(float v) {
    for (int off = 32; off > 0; off >>= 1) v += __shfl_down(v, off, 64);
    return v;
}

// ---------------- f32 -> bf16 convert (x input, once) ----------------
__global__ void k_convert_bf16(const float* __restrict__ in, unsigned short* __restrict__ out,
                               int n4) {
    int i = blockIdx.x * blockDim.x + threadIdx.x;
    int stride = gridDim.x * blockDim.x;
    for (; i < n4; i += stride) {
        float4 v = ((const float4*)in)[i];
        uint2 o;
        o.x = packbf(v.x, v.y);
        o.y = packbf(v.z, v.w);
        ((uint2*)out)[i] = o;
    }
}

// ---------------- W transpose + bf16 convert: Wt[m][k] = bf16(W[k][m]) ----------------
__global__ void k_transpose_bf16(const float* __restrict__ W, unsigned short* __restrict__ Wt,
                                 int K, int M) {
    int idx = blockIdx.x * 256 + threadIdx.x;
    if (idx >= K * M) return;
    int k = idx / M, m_ = idx - k * M;
    Wt[(size_t)m_ * K + k] = f2bf(W[idx]);
}

// ---------------- MFMA GEMM: C[NR,M](bf16) = A[NR,K](bf16) @ Wt[M,K](bf16)^T ----------------
#define LSTR 40  // LDS row stride in shorts (80B: 16B-aligned, bank-spread)
__global__ __launch_bounds__(256) void k_gemm_mfma(const unsigned short* __restrict__ A,
                                                   const unsigned short* __restrict__ Bt,
                                                   unsigned short* __restrict__ C,
                                                   int NR, int K, int M) {
    __shared__ unsigned short As[128 * LSTR];
    __shared__ unsigned short Bs[128 * LSTR];
    int tid = threadIdx.x;
    int wave = tid >> 6, lane = tid & 63;
    int r16 = lane & 15, kg = lane >> 4;
    int wr = wave >> 1, wc = wave & 1;
    int rowBase = blockIdx.y * 128;
    int colBase = blockIdx.x * 128;
    f32x4 acc[4][4] = {};
    for (int k0 = 0; k0 < K; k0 += 32) {
#pragma unroll
        for (int c = 0; c < 2; c++) {
            int ch = tid + c * 256;            // 512 chunks of 8 elems
            int row = ch >> 2, kc = (ch & 3) * 8;
            int rg = rowBase + row;
            bf16x8 v = {};
            if (rg < NR) v = *(const bf16x8*)(A + (size_t)rg * K + k0 + kc);
            *(bf16x8*)&As[row * LSTR + kc] = v;
            bf16x8 bv = *(const bf16x8*)(Bt + (size_t)(colBase + row) * K + k0 + kc);
            *(bf16x8*)&Bs[row * LSTR + kc] = bv;
        }
        __syncthreads();
        bf16x8 af[4], bfr[4];
#pragma unroll
        for (int m = 0; m < 4; m++)
            af[m] = *(const bf16x8*)&As[(wr * 64 + m * 16 + r16) * LSTR + kg * 8];
#pragma unroll
        for (int n = 0; n < 4; n++)
            bfr[n] = *(const bf16x8*)&Bs[(wc * 64 + n * 16 + r16) * LSTR + kg * 8];
#pragma unroll
        for (int m = 0; m < 4; m++)
#pragma unroll
            for (int n = 0; n < 4; n++)
                acc[m][n] = __builtin_amdgcn_mfma_f32_16x16x32_bf16(af[m], bfr[n], acc[m][n], 0, 0, 0);
        __syncthreads();
    }
    int crow0 = rowBase + wr * 64;
    int ccol = colBase + wc * 64 + r16;
#pragma unroll
    for (int m = 0; m < 4; m++) {
#pragma unroll
        for (int j = 0; j < 4; j++) {
            int row = crow0 + m * 16 + kg * 4 + j;
            if (row < NR) {
#pragma unroll
                for (int n = 0; n < 4; n++)
                    C[(size_t)row * M + ccol + n * 16] = f2bf(acc[m][n][j]);
            }
        }
    }
}

// ---------------- attention scores ----------------
__global__ void k_scores(const unsigned short* __restrict__ xl, const float* __restrict__ asrc,
                         const float* __restrict__ adst, float* __restrict__ es,
                         float* __restrict__ ed, int H, int M) {
    int n = blockIdx.x;
    int t = threadIdx.x;
    float v = bf2f(xl[(size_t)n * M + t]);
    float ps = v * asrc[t], pd = v * adst[t];
    ps = waveReduceSum(ps);
    pd = waveReduceSum(pd);
    __shared__ float sS[4], sD[4];
    int wid = t >> 6;
    if ((t & 63) == 0) { sS[wid] = ps; sD[wid] = pd; }
    __syncthreads();
    if (t < H) {
        es[n * H + t] = sS[2 * t] + sS[2 * t + 1];
        ed[n * H + t] = sD[2 * t] + sD[2 * t + 1];
    }
}

// ---------------- fused softmax + aggregation: 1 wave per node ----------------
// Cooperative scoring: each lane scores ONE edge per 64-chunk (not 64x redundant),
// exps parked in wave-private LDS, gather loop reads them via broadcast.
template <int VEC, int H>
__global__ __launch_bounds__(256) void k_aggregate(
        const unsigned short* __restrict__ xl, const float* __restrict__ es,
        const float* __restrict__ ed, const int* __restrict__ offsets,
        const int* __restrict__ count, const int* __restrict__ ssrc,
        const float* __restrict__ bias, unsigned short* __restrict__ out) {
    const int M = 64 * VEC;
    int wid = threadIdx.x >> 6;
    int n = blockIdx.x * 4 + wid;
    if (n >= NN) return;
    int lane = threadIdx.x & 63;
    int c0 = lane * VEC;
    int h = (H == 2) ? (c0 >> 7) : 0;

    float edn0 = ed[n * H + 0];
    float self0 = leaky(es[n * H + 0] + edn0);
    float edn1 = 0.f, self1 = 0.f;
    if (H == 2) {
        edn1 = ed[n * H + 1];
        self1 = leaky(es[n * H + 1] + edn1);
    }
    int s0 = offsets[n], cnt = count[n];

    // ---- pass 1: cooperative max (one edge per lane per chunk) ----
    float mx0 = self0, mx1 = self1;
    for (int base = 0; base < cnt; base += 64) {
        int i = base + lane;
        if (i < cnt) {
            int s = ssrc[s0 + i];
            mx0 = fmaxf(mx0, leaky(es[s * H + 0] + edn0));
            if (H == 2) mx1 = fmaxf(mx1, leaky(es[s * H + 1] + edn1));
        }
    }
#pragma unroll
    for (int off = 32; off > 0; off >>= 1) {
        mx0 = fmaxf(mx0, __shfl_xor(mx0, off, 64));
        if (H == 2) mx1 = fmaxf(mx1, __shfl_xor(mx1, off, 64));
    }

    float mxh = (h == 0) ? mx0 : mx1;
    float selfh = (h == 0) ? self0 : self1;
    float ex_self = __expf(selfh - mxh);

    float acc[VEC];
    {
        const uint32_t* rp = (const uint32_t*)(xl + (size_t)n * M + c0);
#pragma unroll
        for (int v = 0; v < VEC / 2; v++) {
            uint32_t w = rp[v];
            acc[2 * v] = ex_self * bflo(w);
            acc[2 * v + 1] = ex_self * bfhi(w);
        }
    }

    // ---- pass 2: per chunk, score cooperatively -> LDS, then gather ----
    __shared__ int ls[4][64];
    __shared__ float le[4][H][64];
    float den0 = 0.f, den1 = 0.f;  // per-lane partials
    for (int base = 0; base < cnt; base += 64) {
        int i = base + lane;
        int s = 0;
        float e0 = 0.f, e1 = 0.f;
        if (i < cnt) {
            s = ssrc[s0 + i];
            e0 = __expf(leaky(es[s * H + 0] + edn0) - mx0);
            den0 += e0;
            if (H == 2) {
                e1 = __expf(leaky(es[s * H + 1] + edn1) - mx1);
                den1 += e1;
            }
        }
        ls[wid][lane] = s;
        le[wid][0][lane] = e0;
        if (H == 2) le[wid][1][lane] = e1;
        // per-wave DS ops are in-order; just ensure stores land before reads
        asm volatile("s_waitcnt lgkmcnt(0)" ::: "memory");
        int lim = min(64, cnt - base);
        int j = 0;
        for (; j + 2 <= lim; j += 2) {
            int sA = ls[wid][j], sB = ls[wid][j + 1];
            float eA = le[wid][h][j], eB = le[wid][h][j + 1];
            const uint32_t* rA = (const uint32_t*)(xl + (size_t)sA * M + c0);
            const uint32_t* rB = (const uint32_t*)(xl + (size_t)sB * M + c0);
            uint32_t wa[VEC / 2], wb[VEC / 2];
#pragma unroll
            for (int v = 0; v < VEC / 2; v++) wa[v] = rA[v];
#pragma unroll
            for (int v = 0; v < VEC / 2; v++) wb[v] = rB[v];
#pragma unroll
            for (int v = 0; v < VEC / 2; v++) {
                acc[2 * v] += eA * bflo(wa[v]) + eB * bflo(wb[v]);
                acc[2 * v + 1] += eA * bfhi(wa[v]) + eB * bfhi(wb[v]);
            }
        }
        if (j < lim) {
            int sA = ls[wid][j];
            float eA = le[wid][h][j];
            const uint32_t* rA = (const uint32_t*)(xl + (size_t)sA * M + c0);
#pragma unroll
            for (int v = 0; v < VEC / 2; v++) {
                uint32_t w = rA[v];
                acc[2 * v] += eA * bflo(w);
                acc[2 * v + 1] += eA * bfhi(w);
            }
        }
    }

    // ---- reduce den partials across the wave ----
#pragma unroll
    for (int off = 32; off > 0; off >>= 1) {
        den0 += __shfl_xor(den0, off, 64);
        if (H == 2) den1 += __shfl_xor(den1, off, 64);
    }
    float den = ((h == 0) ? den0 : den1) + ex_self + 1e-16f;
    float inv = 1.f / den;
    uint32_t* op = (uint32_t*)(out + (size_t)n * M + c0);
#pragma unroll
    for (int v = 0; v < VEC / 2; v++) {
        float f0 = acc[2 * v] * inv + bias[c0 + 2 * v];
        float f1 = acc[2 * v + 1] * inv + bias[c0 + 2 * v + 1];
        op[v] = packbf(f0, f1);
    }
}

// ---------------- edge sort by dst (counting sort) ----------------
__global__ void k_count(const int* __restrict__ dst, int* __restrict__ count) {
    int e = blockIdx.x * blockDim.x + threadIdx.x;
    if (e < EE) atomicAdd(&count[dst[e]], 1);
}

__global__ void k_scan_local(const int* __restrict__ in, int* __restrict__ out_excl,
                             int* __restrict__ bsums, int n) {
    __shared__ int s[256];
    int tid = threadIdx.x;
    int i = blockIdx.x * 256 + tid;
    int v = (i < n) ? in[i] : 0;
    s[tid] = v;
    __syncthreads();
    for (int off = 1; off < 256; off <<= 1) {
        int t_ = (tid >= off) ? s[tid - off] : 0;
        __syncthreads();
        s[tid] += t_;
        __syncthreads();
    }
    if (i < n) out_excl[i] = s[tid] - v;
    if (tid == 255) bsums[blockIdx.x] = s[255];
}

__global__ void k_scan_sums(int* __restrict__ b, int n) {
    __shared__ int s[256];
    int tid = threadIdx.x;
    int v = (tid < n) ? b[tid] : 0;
    s[tid] = v;
    __syncthreads();
    for (int off = 1; off < 256; off <<= 1) {
        int t_ = (tid >= off) ? s[tid - off] : 0;
        __syncthreads();
        s[tid] += t_;
        __syncthreads();
    }
    if (tid < n) b[tid] = s[tid] - v;
}

__global__ void k_scan_add(int* __restrict__ out_excl, const int* __restrict__ bsums, int n) {
    int i = blockIdx.x * 256 + threadIdx.x;
    if (i < n) out_excl[i] += bsums[blockIdx.x];
}

__global__ void k_scatter(const int* __restrict__ src, const int* __restrict__ dst,
                          const int* __restrict__ offsets, int* __restrict__ cursor,
                          int* __restrict__ ssrc) {
    int e = blockIdx.x * blockDim.x + threadIdx.x;
    if (e >= EE) return;
    int d = dst[e];
    int p = offsets[d] + atomicAdd(&cursor[d], 1);
    ssrc[p] = src[e];
}

// ---------------- batch norm (bf16 data, f32/f64 stats) ----------------
__global__ void k_bn_stats(const unsigned short* __restrict__ h, double* __restrict__ stats) {
    int t = threadIdx.x;  // 256 cols
    int r0 = blockIdx.x * 256;
    int rend = min(r0 + 256, NN);
    double s = 0.0, s2 = 0.0;
    for (int r = r0; r < rend; r++) {
        float v = bf2f(h[(size_t)r * 256 + t]);
        s += v;
        s2 += (double)v * v;
    }
    atomicAdd(&stats[t], s);
    atomicAdd(&stats[256 + t], s2);
}

__global__ void k_bn_finalize(const double* __restrict__ stats, const float* __restrict__ g,
                              const float* __restrict__ be, float* __restrict__ scale,
                              float* __restrict__ shift) {
    int t = threadIdx.x;  // 256
    double mu = stats[t] / (double)NN;
    double var = stats[256 + t] / (double)NN - mu * mu;
    float sc = (float)((double)g[t] / sqrt(var + (double)BN_EPS));
    scale[t] = sc;
    shift[t] = be[t] - (float)mu * sc;
}

__global__ void k_bn_apply(unsigned short* __restrict__ h, const float* __restrict__ scale,
                           const float* __restrict__ shift) {
    int i = blockIdx.x * blockDim.x + threadIdx.x;
    int stride = gridDim.x * blockDim.x;
    int total = NN * 256 / 8;
    uint4* h4 = (uint4*)h;
    for (; i < total; i += stride) {
        uint4 v = h4[i];
        int t = (i * 8) & 255;
        float f0 = fmaxf(bflo(v.x) * scale[t + 0] + shift[t + 0], 0.f);
        float f1 = fmaxf(bfhi(v.x) * scale[t + 1] + shift[t + 1], 0.f);
        float f2 = fmaxf(bflo(v.y) * scale[t + 2] + shift[t + 2], 0.f);
        float f3 = fmaxf(bfhi(v.y) * scale[t + 3] + shift[t + 3], 0.f);
        float f4 = fmaxf(bflo(v.z) * scale[t + 4] + shift[t + 4], 0.f);
        float f5 = fmaxf(bfhi(v.z) * scale[t + 5] + shift[t + 5], 0.f);
        float f6 = fmaxf(bflo(v.w) * scale[t + 6] + shift[t + 6], 0.f);
        float f7 = fmaxf(bfhi(v.w) * scale[t + 7] + shift[t + 7], 0.f);
        v.x = packbf(f0, f1);
        v.y = packbf(f2, f3);
        v.z = packbf(f4, f5);
        v.w = packbf(f6, f7);
        h4[i] = v;
    }
}

// ---------------- pooling + final linear ----------------
#define POOL_ROWS 128
__global__ void k_pool(const unsigned short* __restrict__ h3, const int* __restrict__ batch,
                       float* __restrict__ pooled, int* __restrict__ cnt) {
    int t = threadIdx.x;  // 128
    int r0 = blockIdx.x * POOL_ROWS;
    if (r0 >= NN) return;
    int rend = min(r0 + POOL_ROWS, NN);
    float acc = 0.f;
    int c_acc = 0;
    int g_cur = batch[r0];
    for (int r = r0; r < rend; r++) {
        int g = batch[r];
        if (g != g_cur) {
            atomicAdd(&pooled[g_cur * 128 + t], acc);
            if (t == 0) atomicAdd(&cnt[g_cur], c_acc);
            acc = 0.f;
            c_acc = 0;
            g_cur = g;
        }
        acc += bf2f(h3[(size_t)r * 128 + t]);
        c_acc++;
    }
    atomicAdd(&pooled[g_cur * 128 + t], acc);
    if (t == 0) atomicAdd(&cnt[g_cur], c_acc);
}

__global__ void k_final(const float* __restrict__ pooled, const int* __restrict__ cnt,
                        const float* __restrict__ Wlin, const float* __restrict__ blin,
                        float* __restrict__ out) {
    int g = blockIdx.x;   // 64
    int o = threadIdx.x;  // 64
    float c = (float)max(cnt[g], 1);
    float acc = 0.f;
    for (int k = 0; k < 128; k++) acc += pooled[g * 128 + k] * Wlin[k * 64 + o];
    out[g * 64 + o] = acc / c + blin[o];
}

// ---------------- host ----------------
extern "C" void kernel_launch(void* const* d_in, const int* in_sizes, int n_in,
                              void* d_out, int out_size, void* d_ws, size_t ws_size,
                              hipStream_t stream) {
    const float* x = (const float*)d_in[0];
    const int* ei = (const int*)d_in[1];
    const int* batch = (const int*)d_in[2];
    const float* W1 = (const float*)d_in[3];
    const float* as1 = (const float*)d_in[4];
    const float* ad1 = (const float*)d_in[5];
    const float* b1 = (const float*)d_in[6];
    const float* g1 = (const float*)d_in[7];
    const float* be1 = (const float*)d_in[8];
    const float* W2 = (const float*)d_in[9];
    const float* as2 = (const float*)d_in[10];
    const float* ad2 = (const float*)d_in[11];
    const float* b2 = (const float*)d_in[12];
    const float* g2 = (const float*)d_in[13];
    const float* be2 = (const float*)d_in[14];
    const float* W3 = (const float*)d_in[15];
    const float* as3 = (const float*)d_in[16];
    const float* ad3 = (const float*)d_in[17];
    const float* b3 = (const float*)d_in[18];
    const float* Wlin = (const float*)d_in[19];
    const float* blin = (const float*)d_in[20];
    float* out = (float*)d_out;

    const int* src = ei;
    const int* dst = ei + EE;

    char* ws = (char*)d_ws;
    size_t off = 0;
    auto alloc = [&](size_t bytes) -> void* {
        void* p = (void*)(ws + off);
        off = (off + bytes + 255) & ~(size_t)255;
        return p;
    };
    unsigned short* xb = (unsigned short*)alloc((size_t)NN * 512 * 2);
    unsigned short* xl = (unsigned short*)alloc((size_t)NN * 256 * 2);
    unsigned short* hbuf = (unsigned short*)alloc((size_t)NN * 256 * 2);
    unsigned short* Wt = (unsigned short*)alloc((size_t)256 * 512 * 2);
    float* es = (float*)alloc((size_t)NN * 2 * 4);
    float* ed = (float*)alloc((size_t)NN * 2 * 4);
    int* count = (int*)alloc((size_t)NN * 4);
    int* offsets = (int*)alloc((size_t)NN * 4);
    int* cursor = (int*)alloc((size_t)NN * 4);
    int* ssrc = (int*)alloc((size_t)EE * 4);
    int* bsums = (int*)alloc(256 * 4);
    double* bnstats = (double*)alloc(512 * 8);
    float* bnscale = (float*)alloc(256 * 4);
    float* bnshift = (float*)alloc(256 * 4);
    float* pooled = (float*)alloc(64 * 128 * 4);
    int* cnt = (int*)alloc(64 * 4);

    const int EB = (EE + 255) / 256;  // 3125
    const int NB = (NN + 255) / 256;  // 196

    // ---- convert x to bf16 (once) ----
    k_convert_bf16<<<2048, 256, 0, stream>>>(x, xb, NN * 512 / 4);

    // ---- sort edges by dst (once; graph shared across layers) ----
    k_memset32<<<64, 256, 0, stream>>>(count, 0, NN);
    k_count<<<EB, 256, 0, stream>>>(dst, count);
    k_scan_local<<<NB, 256, 0, stream>>>(count, offsets, bsums, NN);
    k_scan_sums<<<1, 256, 0, stream>>>(bsums, NB);
    k_scan_add<<<NB, 256, 0, stream>>>(offsets, bsums, NN);
    k_memset32<<<64, 256, 0, stream>>>(cursor, 0, NN);
    k_scatter<<<EB, 256, 0, stream>>>(src, dst, offsets, cursor, ssrc);

    auto run_layer = [&](const unsigned short* hin, int K, const float* W, const float* as_,
                         const float* ad_, const float* bias, unsigned short* outbuf, int H) {
        int M = H * 128;
        k_transpose_bf16<<<(K * M + 255) / 256, 256, 0, stream>>>(W, Wt, K, M);
        dim3 gg(M / 128, (NN + 127) / 128);
        k_gemm_mfma<<<gg, 256, 0, stream>>>(hin, Wt, xl, NN, K, M);
        k_scores<<<NN, M, 0, stream>>>(xl, as_, ad_, es, ed, H, M);
        if (H == 2) {
            k_aggregate<4, 2><<<(NN + 3) / 4, 256, 0, stream>>>(xl, es, ed, offsets, count,
                                                                ssrc, bias, outbuf);
        } else {
            k_aggregate<2, 1><<<(NN + 3) / 4, 256, 0, stream>>>(xl, es, ed, offsets, count,
                                                                ssrc, bias, outbuf);
        }
    };

    auto bn_relu = [&](unsigned short* h, const float* g_, const float* be_) {
        k_memset32<<<4, 256, 0, stream>>>((int*)bnstats, 0, 1024);
        k_bn_stats<<<NB, 256, 0, stream>>>(h, bnstats);
        k_bn_finalize<<<1, 256, 0, stream>>>(bnstats, g_, be_, bnscale, bnshift);
        k_bn_apply<<<2048, 256, 0, stream>>>(h, bnscale, bnshift);
    };

    // layer 1: 512 -> [2,128] concat 256
    run_layer(xb, IN_DIM, W1, as1, ad1, b1, hbuf, 2);
    bn_relu(hbuf, g1, be1);
    // layer 2: 256 -> 256
    run_layer(hbuf, 256, W2, as2, ad2, b2, hbuf, 2);
    bn_relu(hbuf, g2, be2);
    // layer 3: 256 -> 128 (1 head, mean == identity)
    run_layer(hbuf, 256, W3, as3, ad3, b3, hbuf, 1);

    // ---- global mean pool + final linear ----
    k_memset32<<<32, 256, 0, stream>>>((int*)pooled, 0, 64 * 128);
    k_memset32<<<1, 64, 0, stream>>>(cnt, 0, 64);
    k_pool<<<(NN + POOL_ROWS - 1) / POOL_ROWS, 128, 0, stream>>>(hbuf, batch, pooled, cnt);
    k_final<<<GG, 64, 0, stream>>>(pooled, cnt, Wlin, blin, out);
}

// Round 5
// 580.698 us; speedup vs baseline: 3.0853x; 1.1042x over previous
//
#include <hip/hip_runtime.h>
#include <cstdint>
#include <math.h>

#define NN 50000
#define EE 800000
#define GG 64
#define NEG_SLOPE 0.2f
#define BN_EPS 1e-5f

typedef short bf16x8 __attribute__((ext_vector_type(8)));
typedef float f32x4 __attribute__((ext_vector_type(4)));

// ---------------- utility ----------------
__global__ void k_memset32(int* p, int val, int n) {
    int i = blockIdx.x * blockDim.x + threadIdx.x;
    int stride = gridDim.x * blockDim.x;
    for (; i < n; i += stride) p[i] = val;
}

__device__ inline float leaky(float x) { return x > 0.f ? x : NEG_SLOPE * x; }

__device__ inline unsigned short f2bf(float f) {
    union { float f; uint32_t u; } v;
    v.f = f;
    uint32_t u = v.u;
    return (unsigned short)((u + 0x7fffu + ((u >> 16) & 1u)) >> 16);
}

__device__ inline float bf2f(unsigned short u) {
    union { uint32_t u; float f; } v;
    v.u = (uint32_t)u << 16;
    return v.f;
}
__device__ inline float bflo(uint32_t u) { return __uint_as_float(u << 16); }
__device__ inline float bfhi(uint32_t u) { return __uint_as_float(u & 0xffff0000u); }
__device__ inline uint32_t packbf(float a, float b) {
    return (uint32_t)f2bf(a) | ((uint32_t)f2bf(b) << 16);
}

// ---------------- W transpose + bf16 convert: Wt[m][k] = bf16(W[k][m]) ----------------
__global__ void k_transpose_bf16(const float* __restrict__ W, unsigned short* __restrict__ Wt,
                                 int K, int M) {
    int idx = blockIdx.x * 256 + threadIdx.x;
    if (idx >= K * M) return;
    int k = idx / M, m_ = idx - k * M;
    Wt[(size_t)m_ * K + k] = f2bf(W[idx]);
}

// ---------------- MFMA GEMM + fused BN-in + fused scores epilogue ----------------
// C[NR,M](bf16) = A[NR,K] @ Wt[M,K]^T ; es/ed[n,h] = sum_c C_f32[n, h*128+c] * a{src,dst}[h,c]
// AMODE: 0 = bf16 A, 1 = f32 A (layer 1), 2 = bf16 A with BN(scale,shift)+ReLU on load
#define LSTR 40  // LDS row stride in shorts (80B: 16B-aligned, bank-spread)
template <int AMODE>
__global__ __launch_bounds__(256) void k_gemm_mfma(
        const void* __restrict__ Ain, const unsigned short* __restrict__ Bt,
        unsigned short* __restrict__ C,
        const float* __restrict__ bnscale, const float* __restrict__ bnshift,
        const float* __restrict__ asrc, const float* __restrict__ adst,
        float* __restrict__ es, float* __restrict__ ed,
        int NR, int K, int M, int H) {
    __shared__ unsigned short As[128 * LSTR];
    __shared__ unsigned short Bs[128 * LSTR];
    __shared__ float esA[2][128], edA[2][128];
    int tid = threadIdx.x;
    int wave = tid >> 6, lane = tid & 63;
    int r16 = lane & 15, kg = lane >> 4;
    int wr = wave >> 1, wc = wave & 1;
    int rowBase = blockIdx.y * 128;
    int colBase = blockIdx.x * 128;
    f32x4 acc[4][4] = {};
    for (int k0 = 0; k0 < K; k0 += 32) {
#pragma unroll
        for (int c = 0; c < 2; c++) {
            int ch = tid + c * 256;  // 512 chunks of 8 elems
            int row = ch >> 2, kc = (ch & 3) * 8;
            int rg = rowBase + row;
            bf16x8 v = {};
            if (rg < NR) {
                if constexpr (AMODE == 0) {
                    v = *(const bf16x8*)((const unsigned short*)Ain + (size_t)rg * K + k0 + kc);
                } else if constexpr (AMODE == 1) {
                    const float4* p = (const float4*)((const float*)Ain + (size_t)rg * K + k0 + kc);
                    float4 f0 = p[0], f1 = p[1];
                    v[0] = (short)f2bf(f0.x); v[1] = (short)f2bf(f0.y);
                    v[2] = (short)f2bf(f0.z); v[3] = (short)f2bf(f0.w);
                    v[4] = (short)f2bf(f1.x); v[5] = (short)f2bf(f1.y);
                    v[6] = (short)f2bf(f1.z); v[7] = (short)f2bf(f1.w);
                } else {
                    bf16x8 raw = *(const bf16x8*)((const unsigned short*)Ain + (size_t)rg * K + k0 + kc);
                    float4 sc0 = *(const float4*)(bnscale + k0 + kc);
                    float4 sc1 = *(const float4*)(bnscale + k0 + kc + 4);
                    float4 sh0 = *(const float4*)(bnshift + k0 + kc);
                    float4 sh1 = *(const float4*)(bnshift + k0 + kc + 4);
                    float f;
                    f = fmaxf(bf2f((unsigned short)raw[0]) * sc0.x + sh0.x, 0.f); v[0] = (short)f2bf(f);
                    f = fmaxf(bf2f((unsigned short)raw[1]) * sc0.y + sh0.y, 0.f); v[1] = (short)f2bf(f);
                    f = fmaxf(bf2f((unsigned short)raw[2]) * sc0.z + sh0.z, 0.f); v[2] = (short)f2bf(f);
                    f = fmaxf(bf2f((unsigned short)raw[3]) * sc0.w + sh0.w, 0.f); v[3] = (short)f2bf(f);
                    f = fmaxf(bf2f((unsigned short)raw[4]) * sc1.x + sh1.x, 0.f); v[4] = (short)f2bf(f);
                    f = fmaxf(bf2f((unsigned short)raw[5]) * sc1.y + sh1.y, 0.f); v[5] = (short)f2bf(f);
                    f = fmaxf(bf2f((unsigned short)raw[6]) * sc1.z + sh1.z, 0.f); v[6] = (short)f2bf(f);
                    f = fmaxf(bf2f((unsigned short)raw[7]) * sc1.w + sh1.w, 0.f); v[7] = (short)f2bf(f);
                }
            }
            *(bf16x8*)&As[row * LSTR + kc] = v;
            bf16x8 bv = *(const bf16x8*)(Bt + (size_t)(colBase + row) * K + k0 + kc);
            *(bf16x8*)&Bs[row * LSTR + kc] = bv;
        }
        __syncthreads();
        bf16x8 af[4], bfr[4];
#pragma unroll
        for (int m = 0; m < 4; m++)
            af[m] = *(const bf16x8*)&As[(wr * 64 + m * 16 + r16) * LSTR + kg * 8];
#pragma unroll
        for (int n = 0; n < 4; n++)
            bfr[n] = *(const bf16x8*)&Bs[(wc * 64 + n * 16 + r16) * LSTR + kg * 8];
#pragma unroll
        for (int m = 0; m < 4; m++)
#pragma unroll
            for (int n = 0; n < 4; n++)
                acc[m][n] = __builtin_amdgcn_mfma_f32_16x16x32_bf16(af[m], bfr[n], acc[m][n], 0, 0, 0);
        __syncthreads();
    }
    // ---- C write ----
    int crow0 = rowBase + wr * 64;
    int ccol = colBase + wc * 64 + r16;
#pragma unroll
    for (int m = 0; m < 4; m++) {
#pragma unroll
        for (int j = 0; j < 4; j++) {
            int row = crow0 + m * 16 + kg * 4 + j;
            if (row < NR) {
#pragma unroll
                for (int n = 0; n < 4; n++)
                    C[(size_t)row * M + ccol + n * 16] = f2bf(acc[m][n][j]);
            }
        }
    }
    // ---- fused attention-score epilogue ----
    int h_blk = colBase >> 7;
    float as_[4], ad_[4];
#pragma unroll
    for (int n = 0; n < 4; n++) {
        int ch = wc * 64 + n * 16 + r16;  // col within head (block is head-aligned)
        as_[n] = asrc[h_blk * 128 + ch];
        ad_[n] = adst[h_blk * 128 + ch];
    }
#pragma unroll
    for (int m = 0; m < 4; m++) {
#pragma unroll
        for (int j = 0; j < 4; j++) {
            float e1 = 0.f, e2 = 0.f;
#pragma unroll
            for (int n = 0; n < 4; n++) {
                e1 += acc[m][n][j] * as_[n];
                e2 += acc[m][n][j] * ad_[n];
            }
#pragma unroll
            for (int mask = 1; mask < 16; mask <<= 1) {
                e1 += __shfl_xor(e1, mask, 64);
                e2 += __shfl_xor(e2, mask, 64);
            }
            if (r16 == 0) {
                int lr = wr * 64 + m * 16 + kg * 4 + j;
                esA[wc][lr] = e1;
                edA[wc][lr] = e2;
            }
        }
    }
    __syncthreads();
    if (tid < 128) {
        int row = rowBase + tid;
        if (row < NR) {
            es[row * H + h_blk] = esA[0][tid] + esA[1][tid];
            ed[row * H + h_blk] = edA[0][tid] + edA[1][tid];
        }
    }
}

// ---------------- fused softmax + aggregation: 1 wave per node, half-wave per edge ----
template <int VEC>
__device__ inline void edge_fma(float* acc, float e, const unsigned short* rp) {
    if constexpr (VEC == 8) {
        uint4 w = *(const uint4*)rp;
        acc[0] += e * bflo(w.x); acc[1] += e * bfhi(w.x);
        acc[2] += e * bflo(w.y); acc[3] += e * bfhi(w.y);
        acc[4] += e * bflo(w.z); acc[5] += e * bfhi(w.z);
        acc[6] += e * bflo(w.w); acc[7] += e * bfhi(w.w);
    } else {
        uint2 w = *(const uint2*)rp;
        acc[0] += e * bflo(w.x); acc[1] += e * bfhi(w.x);
        acc[2] += e * bflo(w.y); acc[3] += e * bfhi(w.y);
    }
}

template <int VEC, int H>  // M = 32*VEC; lanes 0-31 even edges, 32-63 odd edges
__global__ __launch_bounds__(256) void k_aggregate(
        const unsigned short* __restrict__ xl, const float* __restrict__ es,
        const float* __restrict__ ed, const int* __restrict__ offsets,
        const int* __restrict__ count, const int* __restrict__ ssrc,
        const float* __restrict__ bias, unsigned short* __restrict__ out) {
    const int M = 32 * VEC;
    int wid = threadIdx.x >> 6;
    int n = blockIdx.x * 4 + wid;
    if (n >= NN) return;
    int lane = threadIdx.x & 63;
    int half = lane >> 5, l32 = lane & 31;
    int c0 = l32 * VEC;
    int h = (H == 2) ? (c0 >> 7) : 0;

    float edn0 = ed[n * H + 0];
    float self0 = leaky(es[n * H + 0] + edn0);
    float edn1 = 0.f, self1 = 0.f;
    if (H == 2) {
        edn1 = ed[n * H + 1];
        self1 = leaky(es[n * H + 1] + edn1);
    }
    int s0 = offsets[n], cnt = count[n];

    // ---- pass 1: cooperative max (one edge per lane per chunk) ----
    float mx0 = self0, mx1 = self1;
    for (int base = 0; base < cnt; base += 64) {
        int i = base + lane;
        if (i < cnt) {
            int s = ssrc[s0 + i];
            mx0 = fmaxf(mx0, leaky(es[s * H + 0] + edn0));
            if (H == 2) mx1 = fmaxf(mx1, leaky(es[s * H + 1] + edn1));
        }
    }
#pragma unroll
    for (int off = 32; off > 0; off >>= 1) {
        mx0 = fmaxf(mx0, __shfl_xor(mx0, off, 64));
        if (H == 2) mx1 = fmaxf(mx1, __shfl_xor(mx1, off, 64));
    }

    float mxh = (h == 0) ? mx0 : mx1;
    float selfh = (h == 0) ? self0 : self1;
    float ex_self = __expf(selfh - mxh);

    float acc[VEC] = {};
    if (half == 0) edge_fma<VEC>(acc, ex_self, xl + (size_t)n * M + c0);

    // ---- pass 2: cooperative score -> wave LDS, half-wave gather ----
    __shared__ int ls[4][64];
    __shared__ float le[4][H][64];
    float den0 = 0.f, den1 = 0.f;
    for (int base = 0; base < cnt; base += 64) {
        int i = base + lane;
        int s = 0;
        float e0 = 0.f, e1 = 0.f;
        if (i < cnt) {
            s = ssrc[s0 + i];
            e0 = __expf(leaky(es[s * H + 0] + edn0) - mx0);
            den0 += e0;
            if (H == 2) {
                e1 = __expf(leaky(es[s * H + 1] + edn1) - mx1);
                den1 += e1;
            }
        }
        ls[wid][lane] = s;
        le[wid][0][lane] = e0;
        if (H == 2) le[wid][1][lane] = e1;
        asm volatile("s_waitcnt lgkmcnt(0)" ::: "memory");
        int lim = min(64, cnt - base);
        int j = half;
        for (; j + 3 < lim; j += 4) {
            int sA = ls[wid][j];
            float eA = le[wid][h][j];
            int sB = ls[wid][j + 2];
            float eB = le[wid][h][j + 2];
            edge_fma<VEC>(acc, eA, xl + (size_t)sA * M + c0);
            edge_fma<VEC>(acc, eB, xl + (size_t)sB * M + c0);
        }
        for (; j < lim; j += 2) {
            int sA = ls[wid][j];
            float eA = le[wid][h][j];
            edge_fma<VEC>(acc, eA, xl + (size_t)sA * M + c0);
        }
    }

    // ---- reductions ----
#pragma unroll
    for (int off = 32; off > 0; off >>= 1) {
        den0 += __shfl_xor(den0, off, 64);
        if (H == 2) den1 += __shfl_xor(den1, off, 64);
    }
#pragma unroll
    for (int v = 0; v < VEC; v++) acc[v] += __shfl_xor(acc[v], 32, 64);

    float den = ((h == 0) ? den0 : den1) + ex_self + 1e-16f;
    float inv = 1.f / den;
    if (half == 0) {
        unsigned short* op = out + (size_t)n * M + c0;
        if constexpr (VEC == 8) {
            uint4 o;
            o.x = packbf(acc[0] * inv + bias[c0 + 0], acc[1] * inv + bias[c0 + 1]);
            o.y = packbf(acc[2] * inv + bias[c0 + 2], acc[3] * inv + bias[c0 + 3]);
            o.z = packbf(acc[4] * inv + bias[c0 + 4], acc[5] * inv + bias[c0 + 5]);
            o.w = packbf(acc[6] * inv + bias[c0 + 6], acc[7] * inv + bias[c0 + 7]);
            *(uint4*)op = o;
        } else {
            uint2 o;
            o.x = packbf(acc[0] * inv + bias[c0 + 0], acc[1] * inv + bias[c0 + 1]);
            o.y = packbf(acc[2] * inv + bias[c0 + 2], acc[3] * inv + bias[c0 + 3]);
            *(uint2*)op = o;
        }
    }
}

// ---------------- edge sort by dst (counting sort) ----------------
__global__ void k_count(const int* __restrict__ dst, int* __restrict__ count) {
    int e = blockIdx.x * blockDim.x + threadIdx.x;
    if (e < EE) atomicAdd(&count[dst[e]], 1);
}

__global__ void k_scan_local(const int* __restrict__ in, int* __restrict__ out_excl,
                             int* __restrict__ bsums, int n) {
    __shared__ int s[256];
    int tid = threadIdx.x;
    int i = blockIdx.x * 256 + tid;
    int v = (i < n) ? in[i] : 0;
    s[tid] = v;
    __syncthreads();
    for (int off = 1; off < 256; off <<= 1) {
        int t_ = (tid >= off) ? s[tid - off] : 0;
        __syncthreads();
        s[tid] += t_;
        __syncthreads();
    }
    if (i < n) out_excl[i] = s[tid] - v;
    if (tid == 255) bsums[blockIdx.x] = s[255];
}

__global__ void k_scan_sums(int* __restrict__ b, int n) {
    __shared__ int s[256];
    int tid = threadIdx.x;
    int v = (tid < n) ? b[tid] : 0;
    s[tid] = v;
    __syncthreads();
    for (int off = 1; off < 256; off <<= 1) {
        int t_ = (tid >= off) ? s[tid - off] : 0;
        __syncthreads();
        s[tid] += t_;
        __syncthreads();
    }
    if (tid < n) b[tid] = s[tid] - v;
}

__global__ void k_scan_add(int* __restrict__ out_excl, const int* __restrict__ bsums, int n) {
    int i = blockIdx.x * 256 + threadIdx.x;
    if (i < n) out_excl[i] += bsums[blockIdx.x];
}

__global__ void k_scatter(const int* __restrict__ src, const int* __restrict__ dst,
                          const int* __restrict__ offsets, int* __restrict__ cursor,
                          int* __restrict__ ssrc) {
    int e = blockIdx.x * blockDim.x + threadIdx.x;
    if (e >= EE) return;
    int d = dst[e];
    int p = offsets[d] + atomicAdd(&cursor[d], 1);
    ssrc[p] = src[e];
}

// ---------------- batch norm stats (bf16 data, f64 accum) ----------------
__global__ void k_bn_stats(const unsigned short* __restrict__ h, double* __restrict__ stats) {
    int t = threadIdx.x;  // 256 cols
    int r0 = blockIdx.x * 256;
    int rend = min(r0 + 256, NN);
    double s = 0.0, s2 = 0.0;
    for (int r = r0; r < rend; r++) {
        float v = bf2f(h[(size_t)r * 256 + t]);
        s += v;
        s2 += (double)v * v;
    }
    atomicAdd(&stats[t], s);
    atomicAdd(&stats[256 + t], s2);
}

__global__ void k_bn_finalize(const double* __restrict__ stats, const float* __restrict__ g,
                              const float* __restrict__ be, float* __restrict__ scale,
                              float* __restrict__ shift) {
    int t = threadIdx.x;  // 256
    double mu = stats[t] / (double)NN;
    double var = stats[256 + t] / (double)NN - mu * mu;
    float sc = (float)((double)g[t] / sqrt(var + (double)BN_EPS));
    scale[t] = sc;
    shift[t] = be[t] - (float)mu * sc;
}

// ---------------- pooling + final linear ----------------
#define POOL_ROWS 128
__global__ void k_pool(const unsigned short* __restrict__ h3, const int* __restrict__ batch,
                       float* __restrict__ pooled, int* __restrict__ cnt) {
    int t = threadIdx.x;  // 128
    int r0 = blockIdx.x * POOL_ROWS;
    if (r0 >= NN) return;
    int rend = min(r0 + POOL_ROWS, NN);
    float acc = 0.f;
    int c_acc = 0;
    int g_cur = batch[r0];
    for (int r = r0; r < rend; r++) {
        int g = batch[r];
        if (g != g_cur) {
            atomicAdd(&pooled[g_cur * 128 + t], acc);
            if (t == 0) atomicAdd(&cnt[g_cur], c_acc);
            acc = 0.f;
            c_acc = 0;
            g_cur = g;
        }
        acc += bf2f(h3[(size_t)r * 128 + t]);
        c_acc++;
    }
    atomicAdd(&pooled[g_cur * 128 + t], acc);
    if (t == 0) atomicAdd(&cnt[g_cur], c_acc);
}

__global__ void k_final(const float* __restrict__ pooled, const int* __restrict__ cnt,
                        const float* __restrict__ Wlin, const float* __restrict__ blin,
                        float* __restrict__ out) {
    int g = blockIdx.x;   // 64
    int o = threadIdx.x;  // 64
    float c = (float)max(cnt[g], 1);
    float acc = 0.f;
    for (int k = 0; k < 128; k++) acc += pooled[g * 128 + k] * Wlin[k * 64 + o];
    out[g * 64 + o] = acc / c + blin[o];
}

// ---------------- host ----------------
extern "C" void kernel_launch(void* const* d_in, const int* in_sizes, int n_in,
                              void* d_out, int out_size, void* d_ws, size_t ws_size,
                              hipStream_t stream) {
    const float* x = (const float*)d_in[0];
    const int* ei = (const int*)d_in[1];
    const int* batch = (const int*)d_in[2];
    const float* W1 = (const float*)d_in[3];
    const float* as1 = (const float*)d_in[4];
    const float* ad1 = (const float*)d_in[5];
    const float* b1 = (const float*)d_in[6];
    const float* g1 = (const float*)d_in[7];
    const float* be1 = (const float*)d_in[8];
    const float* W2 = (const float*)d_in[9];
    const float* as2 = (const float*)d_in[10];
    const float* ad2 = (const float*)d_in[11];
    const float* b2 = (const float*)d_in[12];
    const float* g2 = (const float*)d_in[13];
    const float* be2 = (const float*)d_in[14];
    const float* W3 = (const float*)d_in[15];
    const float* as3 = (const float*)d_in[16];
    const float* ad3 = (const float*)d_in[17];
    const float* b3 = (const float*)d_in[18];
    const float* Wlin = (const float*)d_in[19];
    const float* blin = (const float*)d_in[20];
    float* out = (float*)d_out;

    const int* src = ei;
    const int* dst = ei + EE;

    char* ws = (char*)d_ws;
    size_t off = 0;
    auto alloc = [&](size_t bytes) -> void* {
        void* p = (void*)(ws + off);
        off = (off + bytes + 255) & ~(size_t)255;
        return p;
    };
    unsigned short* xl = (unsigned short*)alloc((size_t)NN * 256 * 2);
    unsigned short* hbuf = (unsigned short*)alloc((size_t)NN * 256 * 2);
    unsigned short* Wt1 = (unsigned short*)alloc((size_t)256 * 512 * 2);
    unsigned short* Wt2 = (unsigned short*)alloc((size_t)256 * 256 * 2);
    unsigned short* Wt3 = (unsigned short*)alloc((size_t)128 * 256 * 2);
    float* es = (float*)alloc((size_t)NN * 2 * 4);
    float* ed = (float*)alloc((size_t)NN * 2 * 4);
    int* count = (int*)alloc((size_t)NN * 4);
    int* offsets = (int*)alloc((size_t)NN * 4);
    int* cursor = (int*)alloc((size_t)NN * 4);
    int* ssrc = (int*)alloc((size_t)EE * 4);
    int* bsums = (int*)alloc(256 * 4);
    double* bnstats = (double*)alloc(512 * 8);
    float* bnscale = (float*)alloc(256 * 4);
    float* bnshift = (float*)alloc(256 * 4);
    float* pooled = (float*)alloc(64 * 128 * 4);
    int* cnt = (int*)alloc(64 * 4);

    const int EB = (EE + 255) / 256;  // 3125
    const int NB = (NN + 255) / 256;  // 196
    const int AGB = (NN + 3) / 4;     // 12500

    // ---- weight transposes (independent of data) ----
    k_transpose_bf16<<<(512 * 256 + 255) / 256, 256, 0, stream>>>(W1, Wt1, 512, 256);
    k_transpose_bf16<<<(256 * 256 + 255) / 256, 256, 0, stream>>>(W2, Wt2, 256, 256);
    k_transpose_bf16<<<(256 * 128 + 255) / 256, 256, 0, stream>>>(W3, Wt3, 256, 128);

    // ---- sort edges by dst (once; graph shared across layers) ----
    k_memset32<<<64, 256, 0, stream>>>(count, 0, NN);
    k_count<<<EB, 256, 0, stream>>>(dst, count);
    k_scan_local<<<NB, 256, 0, stream>>>(count, offsets, bsums, NN);
    k_scan_sums<<<1, 256, 0, stream>>>(bsums, NB);
    k_scan_add<<<NB, 256, 0, stream>>>(offsets, bsums, NN);
    k_memset32<<<64, 256, 0, stream>>>(cursor, 0, NN);
    k_scatter<<<EB, 256, 0, stream>>>(src, dst, offsets, cursor, ssrc);

    auto bn_stats = [&](unsigned short* h, const float* g_, const float* be_) {
        k_memset32<<<4, 256, 0, stream>>>((int*)bnstats, 0, 1024);
        k_bn_stats<<<NB, 256, 0, stream>>>(h, bnstats);
        k_bn_finalize<<<1, 256, 0, stream>>>(bnstats, g_, be_, bnscale, bnshift);
    };

    dim3 gRows(2, (NN + 127) / 128);
    dim3 gRows1(1, (NN + 127) / 128);

    // ---- layer 1: 512 -> [2,128] concat 256 (f32 A, fused scores) ----
    k_gemm_mfma<1><<<gRows, 256, 0, stream>>>(x, Wt1, xl, nullptr, nullptr,
                                              as1, ad1, es, ed, NN, 512, 256, 2);
    k_aggregate<8, 2><<<AGB, 256, 0, stream>>>(xl, es, ed, offsets, count, ssrc, b1, hbuf);
    bn_stats(hbuf, g1, be1);

    // ---- layer 2: 256 -> 256 (BN+ReLU fused into A staging) ----
    k_gemm_mfma<2><<<gRows, 256, 0, stream>>>(hbuf, Wt2, xl, bnscale, bnshift,
                                              as2, ad2, es, ed, NN, 256, 256, 2);
    k_aggregate<8, 2><<<AGB, 256, 0, stream>>>(xl, es, ed, offsets, count, ssrc, b2, hbuf);
    bn_stats(hbuf, g2, be2);

    // ---- layer 3: 256 -> 128, 1 head ----
    k_gemm_mfma<2><<<gRows1, 256, 0, stream>>>(hbuf, Wt3, xl, bnscale, bnshift,
                                               as3, ad3, es, ed, NN, 256, 128, 1);
    k_aggregate<4, 1><<<AGB, 256, 0, stream>>>(xl, es, ed, offsets, count, ssrc, b3, hbuf);

    // ---- global mean pool + final linear ----
    k_memset32<<<32, 256, 0, stream>>>((int*)pooled, 0, 64 * 128);
    k_memset32<<<1, 64, 0, stream>>>(cnt, 0, 64);
    k_pool<<<(NN + POOL_ROWS - 1) / POOL_ROWS, 128, 0, stream>>>(hbuf, batch, pooled, cnt);
    k_final<<<GG, 64, 0, stream>>>(pooled, cnt, Wlin, blin, out);
}

// Round 6
// 551.439 us; speedup vs baseline: 3.2490x; 1.0531x over previous
//
#include <hip/hip_runtime.h>
#include <cstdint>
#include <math.h>

#define NN 50000
#define EE 800000
#define GG 64
#define NEG_SLOPE 0.2f
#define BN_EPS 1e-5f

typedef short bf16x8 __attribute__((ext_vector_type(8)));
typedef float f32x4 __attribute__((ext_vector_type(4)));

// ---------------- utility ----------------
__global__ void k_memset32(int* p, int val, int n) {
    int i = blockIdx.x * blockDim.x + threadIdx.x;
    int stride = gridDim.x * blockDim.x;
    for (; i < n; i += stride) p[i] = val;
}

__device__ inline float leaky(float x) { return x > 0.f ? x : NEG_SLOPE * x; }

__device__ inline unsigned short f2bf(float f) {
    union { float f; uint32_t u; } v;
    v.f = f;
    uint32_t u = v.u;
    return (unsigned short)((u + 0x7fffu + ((u >> 16) & 1u)) >> 16);
}

__device__ inline float bf2f(unsigned short u) {
    union { uint32_t u; float f; } v;
    v.u = (uint32_t)u << 16;
    return v.f;
}
__device__ inline float bflo(uint32_t u) { return __uint_as_float(u << 16); }
__device__ inline float bfhi(uint32_t u) { return __uint_as_float(u & 0xffff0000u); }
__device__ inline uint32_t packbf(float a, float b) {
    return (uint32_t)f2bf(a) | ((uint32_t)f2bf(b) << 16);
}

// ---------------- W transpose + bf16 convert: Wt[m][k] = bf16(W[k][m]) ----------------
__global__ void k_transpose_bf16(const float* __restrict__ W, unsigned short* __restrict__ Wt,
                                 int K, int M) {
    int idx = blockIdx.x * 256 + threadIdx.x;
    if (idx >= K * M) return;
    int k = idx / M, m_ = idx - k * M;
    Wt[(size_t)m_ * K + k] = f2bf(W[idx]);
}

// ---------------- MFMA GEMM, double-buffered, + fused BN-in + fused scores epilogue ----
// C[NR,M](bf16) = A[NR,K] @ Wt[M,K]^T ; es/ed[n,h] = sum_c C_f32[n,h*128+c]*a{src,dst}[h,c]
// AMODE: 0 = bf16 A, 1 = f32 A (layer 1), 2 = bf16 A with BN(scale,shift)+ReLU on load
#define LSTR 40  // LDS row stride in shorts (80B: 16B-aligned, bank-spread)
template <int AMODE>
__global__ __launch_bounds__(256) void k_gemm_mfma(
        const void* __restrict__ Ain, const unsigned short* __restrict__ Bt,
        unsigned short* __restrict__ C,
        const float* __restrict__ bnscale, const float* __restrict__ bnshift,
        const float* __restrict__ asrc, const float* __restrict__ adst,
        float* __restrict__ es, float* __restrict__ ed,
        int NR, int K, int M, int H) {
    __shared__ unsigned short As[2][128 * LSTR];
    __shared__ unsigned short Bs[2][128 * LSTR];
    __shared__ float esA[2][128], edA[2][128];
    int tid = threadIdx.x;
    int wave = tid >> 6, lane = tid & 63;
    int r16 = lane & 15, kg = lane >> 4;
    int wr = wave >> 1, wc = wave & 1;
    int rowBase = blockIdx.y * 128;
    int colBase = blockIdx.x * 128;

    // staging geometry: chunk c in {0,1}; ch = tid + c*256; row = ch>>2, kc = (ch&3)*8
    int srow[2], skc[2];
    bool sok[2];
    const unsigned short* aP16[2];
    const float* aP32[2];
    const unsigned short* bP[2];
#pragma unroll
    for (int c = 0; c < 2; c++) {
        int ch = tid + c * 256;
        srow[c] = ch >> 2;
        skc[c] = (ch & 3) * 8;
        int rg = rowBase + srow[c];
        sok[c] = rg < NR;
        int rc = (rg < NR) ? rg : (NR - 1);
        if constexpr (AMODE == 1)
            aP32[c] = (const float*)Ain + (size_t)rc * K + skc[c];
        else
            aP16[c] = (const unsigned short*)Ain + (size_t)rc * K + skc[c];
        bP[c] = Bt + (size_t)(colBase + srow[c]) * K + skc[c];
    }

    float4 fa[2][2];
    bf16x8 va[2], vb[2];
    float4 scr[2][2], shr[2][2];

    auto ISSUE = [&](int k0) {
#pragma unroll
        for (int c = 0; c < 2; c++) {
            if constexpr (AMODE == 1) {
                if (sok[c]) {
                    fa[c][0] = *(const float4*)(aP32[c] + k0);
                    fa[c][1] = *(const float4*)(aP32[c] + k0 + 4);
                } else {
                    fa[c][0] = make_float4(0.f, 0.f, 0.f, 0.f);
                    fa[c][1] = make_float4(0.f, 0.f, 0.f, 0.f);
                }
            } else {
                if (sok[c]) va[c] = *(const bf16x8*)(aP16[c] + k0);
                else va[c] = bf16x8{};
            }
            if constexpr (AMODE == 2) {
                scr[c][0] = *(const float4*)(bnscale + k0 + skc[c]);
                scr[c][1] = *(const float4*)(bnscale + k0 + skc[c] + 4);
                shr[c][0] = *(const float4*)(bnshift + k0 + skc[c]);
                shr[c][1] = *(const float4*)(bnshift + k0 + skc[c] + 4);
            }
            vb[c] = *(const bf16x8*)(bP[c] + k0);
        }
    };

    auto WRITE = [&](int buf) {
#pragma unroll
        for (int c = 0; c < 2; c++) {
            bf16x8 v;
            if constexpr (AMODE == 0) {
                v = va[c];
            } else if constexpr (AMODE == 1) {
                v[0] = (short)f2bf(fa[c][0].x); v[1] = (short)f2bf(fa[c][0].y);
                v[2] = (short)f2bf(fa[c][0].z); v[3] = (short)f2bf(fa[c][0].w);
                v[4] = (short)f2bf(fa[c][1].x); v[5] = (short)f2bf(fa[c][1].y);
                v[6] = (short)f2bf(fa[c][1].z); v[7] = (short)f2bf(fa[c][1].w);
            } else {
                float f;
                f = fmaxf(bf2f((unsigned short)va[c][0]) * scr[c][0].x + shr[c][0].x, 0.f); v[0] = (short)f2bf(f);
                f = fmaxf(bf2f((unsigned short)va[c][1]) * scr[c][0].y + shr[c][0].y, 0.f); v[1] = (short)f2bf(f);
                f = fmaxf(bf2f((unsigned short)va[c][2]) * scr[c][0].z + shr[c][0].z, 0.f); v[2] = (short)f2bf(f);
                f = fmaxf(bf2f((unsigned short)va[c][3]) * scr[c][0].w + shr[c][0].w, 0.f); v[3] = (short)f2bf(f);
                f = fmaxf(bf2f((unsigned short)va[c][4]) * scr[c][1].x + shr[c][1].x, 0.f); v[4] = (short)f2bf(f);
                f = fmaxf(bf2f((unsigned short)va[c][5]) * scr[c][1].y + shr[c][1].y, 0.f); v[5] = (short)f2bf(f);
                f = fmaxf(bf2f((unsigned short)va[c][6]) * scr[c][1].z + shr[c][1].z, 0.f); v[6] = (short)f2bf(f);
                f = fmaxf(bf2f((unsigned short)va[c][7]) * scr[c][1].w + shr[c][1].w, 0.f); v[7] = (short)f2bf(f);
            }
            *(bf16x8*)&As[buf][srow[c] * LSTR + skc[c]] = v;
            *(bf16x8*)&Bs[buf][srow[c] * LSTR + skc[c]] = vb[c];
        }
    };

    f32x4 acc[4][4] = {};
    ISSUE(0);
    WRITE(0);
    __syncthreads();
    int nt = K >> 5;
    for (int t = 0; t < nt; ++t) {
        int cur = t & 1;
        if (t + 1 < nt) ISSUE((t + 1) << 5);  // issue next-tile loads BEFORE compute
        bf16x8 af[4], bfr[4];
#pragma unroll
        for (int m = 0; m < 4; m++)
            af[m] = *(const bf16x8*)&As[cur][(wr * 64 + m * 16 + r16) * LSTR + kg * 8];
#pragma unroll
        for (int n = 0; n < 4; n++)
            bfr[n] = *(const bf16x8*)&Bs[cur][(wc * 64 + n * 16 + r16) * LSTR + kg * 8];
#pragma unroll
        for (int m = 0; m < 4; m++)
#pragma unroll
            for (int n = 0; n < 4; n++)
                acc[m][n] = __builtin_amdgcn_mfma_f32_16x16x32_bf16(af[m], bfr[n], acc[m][n], 0, 0, 0);
        if (t + 1 < nt) WRITE(cur ^ 1);  // vmcnt-wait lands here, after MFMA
        __syncthreads();
    }
    // ---- C write ----
    int crow0 = rowBase + wr * 64;
    int ccol = colBase + wc * 64 + r16;
#pragma unroll
    for (int m = 0; m < 4; m++) {
#pragma unroll
        for (int j = 0; j < 4; j++) {
            int row = crow0 + m * 16 + kg * 4 + j;
            if (row < NR) {
#pragma unroll
                for (int n = 0; n < 4; n++)
                    C[(size_t)row * M + ccol + n * 16] = f2bf(acc[m][n][j]);
            }
        }
    }
    // ---- fused attention-score epilogue ----
    int h_blk = colBase >> 7;
    float as_[4], ad_[4];
#pragma unroll
    for (int n = 0; n < 4; n++) {
        int ch = wc * 64 + n * 16 + r16;
        as_[n] = asrc[h_blk * 128 + ch];
        ad_[n] = adst[h_blk * 128 + ch];
    }
#pragma unroll
    for (int m = 0; m < 4; m++) {
#pragma unroll
        for (int j = 0; j < 4; j++) {
            float e1 = 0.f, e2 = 0.f;
#pragma unroll
            for (int n = 0; n < 4; n++) {
                e1 += acc[m][n][j] * as_[n];
                e2 += acc[m][n][j] * ad_[n];
            }
#pragma unroll
            for (int mask = 1; mask < 16; mask <<= 1) {
                e1 += __shfl_xor(e1, mask, 64);
                e2 += __shfl_xor(e2, mask, 64);
            }
            if (r16 == 0) {
                int lr = wr * 64 + m * 16 + kg * 4 + j;
                esA[wc][lr] = e1;
                edA[wc][lr] = e2;
            }
        }
    }
    __syncthreads();
    if (tid < 128) {
        int row = rowBase + tid;
        if (row < NR) {
            es[row * H + h_blk] = esA[0][tid] + esA[1][tid];
            ed[row * H + h_blk] = edA[0][tid] + edA[1][tid];
        }
    }
}

// ---------------- fused softmax + aggregation: 1 wave per node, half-wave per edge ----
template <int VEC>
__device__ inline void edge_fma(float* acc, float e, const unsigned short* rp) {
    if constexpr (VEC == 8) {
        uint4 w = *(const uint4*)rp;
        acc[0] += e * bflo(w.x); acc[1] += e * bfhi(w.x);
        acc[2] += e * bflo(w.y); acc[3] += e * bfhi(w.y);
        acc[4] += e * bflo(w.z); acc[5] += e * bfhi(w.z);
        acc[6] += e * bflo(w.w); acc[7] += e * bfhi(w.w);
    } else {
        uint2 w = *(const uint2*)rp;
        acc[0] += e * bflo(w.x); acc[1] += e * bfhi(w.x);
        acc[2] += e * bflo(w.y); acc[3] += e * bfhi(w.y);
    }
}

template <int VEC, int H>  // M = 32*VEC; lanes 0-31 even edges, 32-63 odd edges
__global__ __launch_bounds__(256) void k_aggregate(
        const unsigned short* __restrict__ xl, const float* __restrict__ es,
        const float* __restrict__ ed, const int* __restrict__ offsets,
        const int* __restrict__ count, const int* __restrict__ ssrc,
        const float* __restrict__ bias, unsigned short* __restrict__ out) {
    const int M = 32 * VEC;
    int wid = threadIdx.x >> 6;
    int n = blockIdx.x * 4 + wid;
    if (n >= NN) return;
    int lane = threadIdx.x & 63;
    int half = lane >> 5, l32 = lane & 31;
    int c0 = l32 * VEC;
    int h = (H == 2) ? (c0 >> 7) : 0;

    float edn0 = ed[n * H + 0];
    float self0 = leaky(es[n * H + 0] + edn0);
    float edn1 = 0.f, self1 = 0.f;
    if (H == 2) {
        edn1 = ed[n * H + 1];
        self1 = leaky(es[n * H + 1] + edn1);
    }
    int s0 = offsets[n], cnt = count[n];

    // ---- pass 1: cooperative max ----
    float mx0 = self0, mx1 = self1;
    for (int base = 0; base < cnt; base += 64) {
        int i = base + lane;
        if (i < cnt) {
            int s = ssrc[s0 + i];
            mx0 = fmaxf(mx0, leaky(es[s * H + 0] + edn0));
            if (H == 2) mx1 = fmaxf(mx1, leaky(es[s * H + 1] + edn1));
        }
    }
#pragma unroll
    for (int off = 32; off > 0; off >>= 1) {
        mx0 = fmaxf(mx0, __shfl_xor(mx0, off, 64));
        if (H == 2) mx1 = fmaxf(mx1, __shfl_xor(mx1, off, 64));
    }

    float mxh = (h == 0) ? mx0 : mx1;
    float selfh = (h == 0) ? self0 : self1;
    float ex_self = __expf(selfh - mxh);

    float acc[VEC] = {};
    if (half == 0) edge_fma<VEC>(acc, ex_self, xl + (size_t)n * M + c0);

    // ---- pass 2: cooperative score -> wave LDS, half-wave gather ----
    __shared__ int ls[4][64];
    __shared__ float le[4][H][64];
    float den0 = 0.f, den1 = 0.f;
    for (int base = 0; base < cnt; base += 64) {
        int i = base + lane;
        int s = 0;
        float e0 = 0.f, e1 = 0.f;
        if (i < cnt) {
            s = ssrc[s0 + i];
            e0 = __expf(leaky(es[s * H + 0] + edn0) - mx0);
            den0 += e0;
            if (H == 2) {
                e1 = __expf(leaky(es[s * H + 1] + edn1) - mx1);
                den1 += e1;
            }
        }
        ls[wid][lane] = s;
        le[wid][0][lane] = e0;
        if (H == 2) le[wid][1][lane] = e1;
        asm volatile("s_waitcnt lgkmcnt(0)" ::: "memory");
        int lim = min(64, cnt - base);
        int j = half;
        for (; j + 3 < lim; j += 4) {
            int sA = ls[wid][j];
            float eA = le[wid][h][j];
            int sB = ls[wid][j + 2];
            float eB = le[wid][h][j + 2];
            edge_fma<VEC>(acc, eA, xl + (size_t)sA * M + c0);
            edge_fma<VEC>(acc, eB, xl + (size_t)sB * M + c0);
        }
        for (; j < lim; j += 2) {
            int sA = ls[wid][j];
            float eA = le[wid][h][j];
            edge_fma<VEC>(acc, eA, xl + (size_t)sA * M + c0);
        }
    }

    // ---- reductions ----
#pragma unroll
    for (int off = 32; off > 0; off >>= 1) {
        den0 += __shfl_xor(den0, off, 64);
        if (H == 2) den1 += __shfl_xor(den1, off, 64);
    }
#pragma unroll
    for (int v = 0; v < VEC; v++) acc[v] += __shfl_xor(acc[v], 32, 64);

    float den = ((h == 0) ? den0 : den1) + ex_self + 1e-16f;
    float inv = 1.f / den;
    if (half == 0) {
        unsigned short* op = out + (size_t)n * M + c0;
        if constexpr (VEC == 8) {
            uint4 o;
            o.x = packbf(acc[0] * inv + bias[c0 + 0], acc[1] * inv + bias[c0 + 1]);
            o.y = packbf(acc[2] * inv + bias[c0 + 2], acc[3] * inv + bias[c0 + 3]);
            o.z = packbf(acc[4] * inv + bias[c0 + 4], acc[5] * inv + bias[c0 + 5]);
            o.w = packbf(acc[6] * inv + bias[c0 + 6], acc[7] * inv + bias[c0 + 7]);
            *(uint4*)op = o;
        } else {
            uint2 o;
            o.x = packbf(acc[0] * inv + bias[c0 + 0], acc[1] * inv + bias[c0 + 1]);
            o.y = packbf(acc[2] * inv + bias[c0 + 2], acc[3] * inv + bias[c0 + 3]);
            *(uint2*)op = o;
        }
    }
}

// ---------------- edge sort by dst (counting sort) ----------------
__global__ void k_count(const int* __restrict__ dst, int* __restrict__ count) {
    int e = blockIdx.x * blockDim.x + threadIdx.x;
    if (e < EE) atomicAdd(&count[dst[e]], 1);
}

__global__ void k_scan_local(const int* __restrict__ in, int* __restrict__ out_excl,
                             int* __restrict__ bsums, int n) {
    __shared__ int s[256];
    int tid = threadIdx.x;
    int i = blockIdx.x * 256 + tid;
    int v = (i < n) ? in[i] : 0;
    s[tid] = v;
    __syncthreads();
    for (int off = 1; off < 256; off <<= 1) {
        int t_ = (tid >= off) ? s[tid - off] : 0;
        __syncthreads();
        s[tid] += t_;
        __syncthreads();
    }
    if (i < n) out_excl[i] = s[tid] - v;
    if (tid == 255) bsums[blockIdx.x] = s[255];
}

__global__ void k_scan_sums(int* __restrict__ b, int n) {
    __shared__ int s[256];
    int tid = threadIdx.x;
    int v = (tid < n) ? b[tid] : 0;
    s[tid] = v;
    __syncthreads();
    for (int off = 1; off < 256; off <<= 1) {
        int t_ = (tid >= off) ? s[tid - off] : 0;
        __syncthreads();
        s[tid] += t_;
        __syncthreads();
    }
    if (tid < n) b[tid] = s[tid] - v;
}

__global__ void k_scan_add(int* __restrict__ out_excl, const int* __restrict__ bsums, int n) {
    int i = blockIdx.x * 256 + threadIdx.x;
    if (i < n) out_excl[i] += bsums[blockIdx.x];
}

__global__ void k_scatter(const int* __restrict__ src, const int* __restrict__ dst,
                          const int* __restrict__ offsets, int* __restrict__ cursor,
                          int* __restrict__ ssrc) {
    int e = blockIdx.x * blockDim.x + threadIdx.x;
    if (e >= EE) return;
    int d = dst[e];
    int p = offsets[d] + atomicAdd(&cursor[d], 1);
    ssrc[p] = src[e];
}

// ---------------- batch norm stats (bf16 data, f64 accum) ----------------
__global__ void k_bn_stats(const unsigned short* __restrict__ h, double* __restrict__ stats) {
    int t = threadIdx.x;  // 256 cols
    int r0 = blockIdx.x * 256;
    int rend = min(r0 + 256, NN);
    double s = 0.0, s2 = 0.0;
    for (int r = r0; r < rend; r++) {
        float v = bf2f(h[(size_t)r * 256 + t]);
        s += v;
        s2 += (double)v * v;
    }
    atomicAdd(&stats[t], s);
    atomicAdd(&stats[256 + t], s2);
}

__global__ void k_bn_finalize(const double* __restrict__ stats, const float* __restrict__ g,
                              const float* __restrict__ be, float* __restrict__ scale,
                              float* __restrict__ shift) {
    int t = threadIdx.x;  // 256
    double mu = stats[t] / (double)NN;
    double var = stats[256 + t] / (double)NN - mu * mu;
    float sc = (float)((double)g[t] / sqrt(var + (double)BN_EPS));
    scale[t] = sc;
    shift[t] = be[t] - (float)mu * sc;
}

// ---------------- pooling + final linear ----------------
#define POOL_ROWS 128
__global__ void k_pool(const unsigned short* __restrict__ h3, const int* __restrict__ batch,
                       float* __restrict__ pooled, int* __restrict__ cnt) {
    int t = threadIdx.x;  // 128
    int r0 = blockIdx.x * POOL_ROWS;
    if (r0 >= NN) return;
    int rend = min(r0 + POOL_ROWS, NN);
    float acc = 0.f;
    int c_acc = 0;
    int g_cur = batch[r0];
    for (int r = r0; r < rend; r++) {
        int g = batch[r];
        if (g != g_cur) {
            atomicAdd(&pooled[g_cur * 128 + t], acc);
            if (t == 0) atomicAdd(&cnt[g_cur], c_acc);
            acc = 0.f;
            c_acc = 0;
            g_cur = g;
        }
        acc += bf2f(h3[(size_t)r * 128 + t]);
        c_acc++;
    }
    atomicAdd(&pooled[g_cur * 128 + t], acc);
    if (t == 0) atomicAdd(&cnt[g_cur], c_acc);
}

__global__ void k_final(const float* __restrict__ pooled, const int* __restrict__ cnt,
                        const float* __restrict__ Wlin, const float* __restrict__ blin,
                        float* __restrict__ out) {
    int g = blockIdx.x;   // 64
    int o = threadIdx.x;  // 64
    float c = (float)max(cnt[g], 1);
    float acc = 0.f;
    for (int k = 0; k < 128; k++) acc += pooled[g * 128 + k] * Wlin[k * 64 + o];
    out[g * 64 + o] = acc / c + blin[o];
}

// ---------------- host ----------------
extern "C" void kernel_launch(void* const* d_in, const int* in_sizes, int n_in,
                              void* d_out, int out_size, void* d_ws, size_t ws_size,
                              hipStream_t stream) {
    const float* x = (const float*)d_in[0];
    const int* ei = (const int*)d_in[1];
    const int* batch = (const int*)d_in[2];
    const float* W1 = (const float*)d_in[3];
    const float* as1 = (const float*)d_in[4];
    const float* ad1 = (const float*)d_in[5];
    const float* b1 = (const float*)d_in[6];
    const float* g1 = (const float*)d_in[7];
    const float* be1 = (const float*)d_in[8];
    const float* W2 = (const float*)d_in[9];
    const float* as2 = (const float*)d_in[10];
    const float* ad2 = (const float*)d_in[11];
    const float* b2 = (const float*)d_in[12];
    const float* g2 = (const float*)d_in[13];
    const float* be2 = (const float*)d_in[14];
    const float* W3 = (const float*)d_in[15];
    const float* as3 = (const float*)d_in[16];
    const float* ad3 = (const float*)d_in[17];
    const float* b3 = (const float*)d_in[18];
    const float* Wlin = (const float*)d_in[19];
    const float* blin = (const float*)d_in[20];
    float* out = (float*)d_out;

    const int* src = ei;
    const int* dst = ei + EE;

    char* ws = (char*)d_ws;
    size_t off = 0;
    auto alloc = [&](size_t bytes) -> void* {
        void* p = (void*)(ws + off);
        off = (off + bytes + 255) & ~(size_t)255;
        return p;
    };
    unsigned short* xl = (unsigned short*)alloc((size_t)NN * 256 * 2);
    unsigned short* hbuf = (unsigned short*)alloc((size_t)NN * 256 * 2);
    unsigned short* Wt1 = (unsigned short*)alloc((size_t)256 * 512 * 2);
    unsigned short* Wt2 = (unsigned short*)alloc((size_t)256 * 256 * 2);
    unsigned short* Wt3 = (unsigned short*)alloc((size_t)128 * 256 * 2);
    float* es = (float*)alloc((size_t)NN * 2 * 4);
    float* ed = (float*)alloc((size_t)NN * 2 * 4);
    int* count = (int*)alloc((size_t)NN * 4);
    int* offsets = (int*)alloc((size_t)NN * 4);
    int* cursor = (int*)alloc((size_t)NN * 4);
    int* ssrc = (int*)alloc((size_t)EE * 4);
    int* bsums = (int*)alloc(256 * 4);
    double* bnstats = (double*)alloc(512 * 8);
    float* bnscale = (float*)alloc(256 * 4);
    float* bnshift = (float*)alloc(256 * 4);
    float* pooled = (float*)alloc(64 * 128 * 4);
    int* cnt = (int*)alloc(64 * 4);

    const int EB = (EE + 255) / 256;  // 3125
    const int NB = (NN + 255) / 256;  // 196
    const int AGB = (NN + 3) / 4;     // 12500

    // ---- weight transposes ----
    k_transpose_bf16<<<(512 * 256 + 255) / 256, 256, 0, stream>>>(W1, Wt1, 512, 256);
    k_transpose_bf16<<<(256 * 256 + 255) / 256, 256, 0, stream>>>(W2, Wt2, 256, 256);
    k_transpose_bf16<<<(256 * 128 + 255) / 256, 256, 0, stream>>>(W3, Wt3, 256, 128);

    // ---- sort edges by dst (once; graph shared across layers) ----
    k_memset32<<<64, 256, 0, stream>>>(count, 0, NN);
    k_count<<<EB, 256, 0, stream>>>(dst, count);
    k_scan_local<<<NB, 256, 0, stream>>>(count, offsets, bsums, NN);
    k_scan_sums<<<1, 256, 0, stream>>>(bsums, NB);
    k_scan_add<<<NB, 256, 0, stream>>>(offsets, bsums, NN);
    k_memset32<<<64, 256, 0, stream>>>(cursor, 0, NN);
    k_scatter<<<EB, 256, 0, stream>>>(src, dst, offsets, cursor, ssrc);

    auto bn_stats = [&](unsigned short* h, const float* g_, const float* be_) {
        k_memset32<<<4, 256, 0, stream>>>((int*)bnstats, 0, 1024);
        k_bn_stats<<<NB, 256, 0, stream>>>(h, bnstats);
        k_bn_finalize<<<1, 256, 0, stream>>>(bnstats, g_, be_, bnscale, bnshift);
    };

    dim3 gRows(2, (NN + 127) / 128);
    dim3 gRows1(1, (NN + 127) / 128);

    // ---- layer 1: 512 -> [2,128] concat 256 (f32 A, fused scores) ----
    k_gemm_mfma<1><<<gRows, 256, 0, stream>>>(x, Wt1, xl, nullptr, nullptr,
                                              as1, ad1, es, ed, NN, 512, 256, 2);
    k_aggregate<8, 2><<<AGB, 256, 0, stream>>>(xl, es, ed, offsets, count, ssrc, b1, hbuf);
    bn_stats(hbuf, g1, be1);

    // ---- layer 2: 256 -> 256 (BN+ReLU fused into A staging) ----
    k_gemm_mfma<2><<<gRows, 256, 0, stream>>>(hbuf, Wt2, xl, bnscale, bnshift,
                                              as2, ad2, es, ed, NN, 256, 256, 2);
    k_aggregate<8, 2><<<AGB, 256, 0, stream>>>(xl, es, ed, offsets, count, ssrc, b2, hbuf);
    bn_stats(hbuf, g2, be2);

    // ---- layer 3: 256 -> 128, 1 head ----
    k_gemm_mfma<2><<<gRows1, 256, 0, stream>>>(hbuf, Wt3, xl, bnscale, bnshift,
                                               as3, ad3, es, ed, NN, 256, 128, 1);
    k_aggregate<4, 1><<<AGB, 256, 0, stream>>>(xl, es, ed, offsets, count, ssrc, b3, hbuf);

    // ---- global mean pool + final linear ----
    k_memset32<<<32, 256, 0, stream>>>((int*)pooled, 0, 64 * 128);
    k_memset32<<<1, 64, 0, stream>>>(cnt, 0, 64);
    k_pool<<<(NN + POOL_ROWS - 1) / POOL_ROWS, 128, 0, stream>>>(hbuf, batch, pooled, cnt);
    k_final<<<GG, 64, 0, stream>>>(pooled, cnt, Wlin, blin, out);
}